// Round 6
// baseline (1705.002 us; speedup 1.0000x reference)
//
#include <hip/hip_runtime.h>

// PointNetSAModule on MI355X (gfx950).
// B=16, N=8192, CIN=64, S=1024, K=32, radius=0.2, MLP 67->64->64->128, eps=1e-5.
// Inputs/outputs float32. ws >= 17.9 MB proven (R14).
//
// R20 -> R21: REVERT the prep/transpose fusion (measured net loss: fused fps
// window 982us vs 900 standalone; interference cost 82us > the ~25us serial
// saving). KEEP the fps tail candidate-coords prefetch from R20, now isolated
// for a clean A/B vs R19's 900us:
//   after {kv,ki} return from LDS, lanes 0-15 read wave-l16's candidate
//   coords from sc[] CONCURRENTLY with the 8-level DPP reduce; winner coords
//   selected by 3 v_readlane(.., wwv) instead of a dependent sc[] read.
// prep/transpose/ballq/MLP identical to R19 (= R15 forms).

typedef unsigned short u16;
typedef unsigned int   u32;
typedef unsigned long long u64;

#define NB    16
#define NPTS  8192
#define CINF  64
#define NS    1024
#define KK    32
#define NSAMP (NB*NS*KK)   // 524288

typedef _Float16 h2v   __attribute__((ext_vector_type(2)));
typedef _Float16 f16x8 __attribute__((ext_vector_type(8)));
typedef float    f32x4 __attribute__((ext_vector_type(4)));
typedef float    f32x2 __attribute__((ext_vector_type(2)));

static __device__ __forceinline__ h2v asH2(u32 x){ union{u32 u; h2v h;} v; v.u=x; return v.h; }
static __device__ __forceinline__ u32 asU32(h2v h){ union{u32 u; h2v h;} v; v.h=h; return v.u; }
static __device__ __forceinline__ u32 packh(float lo, float hi){
  union{ _Float16 h[2]; u32 u; } v;
  v.h[0]=(_Float16)lo; v.h[1]=(_Float16)hi; return v.u;
}
static __device__ __forceinline__ u16 f16b(float z){
  union{ _Float16 h; u16 s; } v; v.h=(_Float16)z; return v.s;
}
static __device__ __forceinline__ f32x4 zero4(){ f32x4 z; z[0]=0.f;z[1]=0.f;z[2]=0.f;z[3]=0.f; return z; }
static __device__ __forceinline__ f16x8 zero8h(){
  f16x8 z;
  #pragma unroll
  for (int i=0;i<8;i++) z[i]=(_Float16)0.f;
  return z;
}

// exact-order d^2, matching numpy f32: (dx*dx + dy*dy) + dz*dz, no FMA contraction
static __device__ __forceinline__ float d2_exact(float ax,float ay,float az,float bx,float by,float bz){
  float dx=__fsub_rn(ax,bx), dy=__fsub_rn(ay,by), dz=__fsub_rn(az,bz);
  return __fadd_rn(__fadd_rn(__fmul_rn(dx,dx),__fmul_rn(dy,dy)),__fmul_rn(dz,dz));
}

// DPP helpers (VALU pipe)
template<int CTRL, int RMASK>
static __device__ __forceinline__ float dppfmax1(float v){
  int o = __builtin_amdgcn_update_dpp(__float_as_int(v), __float_as_int(v),
                                      CTRL, RMASK, 0xf, false);
  return fmaxf(v, __int_as_float(o));
}
template<int CTRL, int RMASK>
static __device__ __forceinline__ float dppfmin1(float v){
  int o = __builtin_amdgcn_update_dpp(__float_as_int(v), __float_as_int(v),
                                      CTRL, RMASK, 0xf, false);
  return fminf(v, __int_as_float(o));
}
template<int CTRL, int RMASK>
static __device__ __forceinline__ u32 dppumax1(u32 v){
  u32 o = (u32)__builtin_amdgcn_update_dpp((int)v, (int)v, CTRL, RMASK, 0xf, false);
  return v > o ? v : o;
}
#define RED6MAX(v) { v=dppfmax1<0xB1,0xf>(v); v=dppfmax1<0x4E,0xf>(v); v=dppfmax1<0x141,0xf>(v); \
                     v=dppfmax1<0x140,0xf>(v); v=dppfmax1<0x142,0xa>(v); v=dppfmax1<0x143,0xc>(v); }
#define RED6MIN(v) { v=dppfmin1<0xB1,0xf>(v); v=dppfmin1<0x4E,0xf>(v); v=dppfmin1<0x141,0xf>(v); \
                     v=dppfmin1<0x140,0xf>(v); v=dppfmin1<0x142,0xa>(v); v=dppfmin1<0x143,0xc>(v); }
#define RED6UMAX(v) { v=dppumax1<0xB1,0xf>(v); v=dppumax1<0x4E,0xf>(v); v=dppumax1<0x141,0xf>(v); \
                      v=dppumax1<0x140,0xf>(v); v=dppumax1<0x142,0xa>(v); v=dppumax1<0x143,0xc>(v); }
// 4-level (within-row-of-16) full reduce: every lane of each 16-lane row
// ends holding the row max.
#define RED4MAXROW(v) { v=dppfmax1<0xB1,0xf>(v); v=dppfmax1<0x4E,0xf>(v); \
                        v=dppfmax1<0x141,0xf>(v); v=dppfmax1<0x140,0xf>(v); }
#define RED4UMAXROW(v) { v=dppumax1<0xB1,0xf>(v); v=dppumax1<0x4E,0xf>(v); \
                         v=dppumax1<0x141,0xf>(v); v=dppumax1<0x140,0xf>(v); }

// ---------------------------------------------------------------- prep ----
__global__ void prep_kernel(const float* __restrict__ W0, const float* __restrict__ W1,
                            const float* __restrict__ W2,
                            u32* __restrict__ Wf1, u32* __restrict__ Wf2, u32* __restrict__ Wf3,
                            float* __restrict__ stats)
{
  const int t = threadIdx.x;
  for (int i=t;i<768;i+=256) stats[i]=0.f;
  for (int i=t;i<2048;i+=256){           // L1: 4 tiles x 2 chunks (feat cols only)
    int d=i&3, lane=(i>>2)&63, kc=(i>>8)&1, tc=i>>9;
    int row=tc*16+(lane&15), k0=kc*32+(lane>>4)*8+2*d;
    Wf1[i]=packh(W0[row*67+3+k0], W0[row*67+4+k0]);
  }
  for (int i=t;i<2048;i+=256){           // L2
    int d=i&3, lane=(i>>2)&63, kc=(i>>8)&1, tc=i>>9;
    int row=tc*16+(lane&15), k0=kc*32+(lane>>4)*8+2*d;
    Wf2[i]=packh(W1[row*64+k0], W1[row*64+k0+1]);
  }
  for (int i=t;i<4096;i+=256){           // L3
    int d=i&3, lane=(i>>2)&63, kc=(i>>8)&1, tc=i>>9;
    int row=tc*16+(lane&15), k0=kc*32+(lane>>4)*8+2*d;
    Wf3[i]=packh(W2[row*64+k0], W2[row*64+k0+1]);
  }
}

// ----------------------------------------------------- feat transpose ----
__global__ __launch_bounds__(256) void transpose_kernel(const float* __restrict__ feat,
                                                        u32* __restrict__ fT32)
{
  __shared__ u16 tile[64][65];
  const int b  = blockIdx.x >> 7;
  const int n0 = (blockIdx.x & 127) << 6;
  const int t = threadIdx.x;
  const int ln = t & 63, lc = t >> 6;
  #pragma unroll
  for (int cc=0; cc<64; cc+=4){
    const int c = cc + lc;
    tile[c][ln] = f16b(feat[((size_t)b*64 + c)*NPTS + n0 + ln]);
  }
  __syncthreads();
  #pragma unroll
  for (int i=0;i<8;i++){
    const int idx = t*8 + i;
    const int row = idx >> 5, dw = idx & 31;
    u32 pair = (u32)tile[2*dw][row] | ((u32)tile[2*dw+1][row] << 16);
    fT32[((size_t)b*NPTS + n0 + row)*32 + dw] = pair;
  }
}

// ----------------------------------------------------------------- FPS ----
// one block per batch; 1024 threads. Morton sort -> wave-compact regions,
// wave bbox prune (no-op skip). Update path entirely in registers; tail is
// value-then-match DPP over 16 wave records with candidate-coords prefetch
// (issued concurrently with the DPP reduce) + readlane winner broadcast.
// No global ops inside the step loop; coalesced epilogue center store.
__global__ __launch_bounds__(1024,1) void fps_kernel(const float* __restrict__ xyz,
    float* __restrict__ out_xyz)
{
  __shared__ float sc[1024*28];            // sorted coords: 8/thread x8|y8|z8|pad4
  __shared__ u16  sidx[NPTS];              // sorted slot -> orig idx
  __shared__ u32  hcnt[64], hoff[64];
  __shared__ u32  s_kv[2][16], s_ki[2][16];
  const int b = blockIdx.x, t = threadIdx.x;
  const float* xb = xyz + (size_t)b*3*NPTS;
  if (t<64) hcnt[t]=0;
  __syncthreads();
  // ---- pass 1: load (coalesced), Morton cell, histogram ----
  float lx[8], ly[8], lz[8]; int lcell[8];
  #pragma unroll
  for (int i=0;i<8;i++){
    const int idx = t + 1024*i;
    float x=xb[idx], y=xb[NPTS+idx], z=xb[2*NPTS+idx];
    lx[i]=x; ly[i]=y; lz[i]=z;
    int ix=(int)(x*4.f); ix = ix<0?0:(ix>3?3:ix);
    int iy=(int)(y*4.f); iy = iy<0?0:(iy>3?3:iy);
    int iz=(int)(z*4.f); iz = iz<0?0:(iz>3?3:iz);
    int m = (ix&1)|((iy&1)<<1)|((iz&1)<<2)|((ix&2)<<2)|((iy&2)<<3)|((iz&2)<<4);
    lcell[i]=m;
    atomicAdd(&hcnt[m],1u);
  }
  __syncthreads();
  if (t==0){ u32 s=0; for (int c=0;c<64;c++){ hoff[c]=s; s+=hcnt[c]; } }
  __syncthreads();
  // ---- scatter into sorted LDS layout ----
  #pragma unroll
  for (int i=0;i<8;i++){
    u32 pos = atomicAdd(&hoff[lcell[i]],1u);
    const int rb=(int)(pos>>3)*28+(int)(pos&7);
    sc[rb]=lx[i]; sc[rb+8]=ly[i]; sc[rb+16]=lz[i];
    sidx[pos]=(u16)(t+1024*i);
  }
  __syncthreads();
  // ---- pull this thread's 8 sorted points into registers; sc[] remains
  //      valid for the tail's candidate-coord prefetch ----
  const int tb = t*28;
  const f32x4 X0=*(const f32x4*)&sc[tb],   X1=*(const f32x4*)&sc[tb+4];
  const f32x4 Y0=*(const f32x4*)&sc[tb+8], Y1=*(const f32x4*)&sc[tb+12];
  const f32x4 Z0=*(const f32x4*)&sc[tb+16],Z1=*(const f32x4*)&sc[tb+20];
  // ---- wave bbox ----
  float mnx,mxx,mny,mxy,mnz,mxz;
  {
    mnx=mxx=X0[0]; mny=mxy=Y0[0]; mnz=mxz=Z0[0];
    #pragma unroll
    for (int i=0;i<4;i++){
      mnx=fminf(mnx,fminf(X0[i],X1[i])); mxx=fmaxf(mxx,fmaxf(X0[i],X1[i]));
      mny=fminf(mny,fminf(Y0[i],Y1[i])); mxy=fmaxf(mxy,fmaxf(Y0[i],Y1[i]));
      mnz=fminf(mnz,fminf(Z0[i],Z1[i])); mxz=fmaxf(mxz,fmaxf(Z0[i],Z1[i]));
    }
  }
  RED6MIN(mnx) RED6MIN(mny) RED6MIN(mnz)
  RED6MAX(mxx) RED6MAX(mxy) RED6MAX(mxz)
  const float bx0=__int_as_float(__builtin_amdgcn_readlane(__float_as_int(mnx),63));
  const float bx1=__int_as_float(__builtin_amdgcn_readlane(__float_as_int(mxx),63));
  const float by0=__int_as_float(__builtin_amdgcn_readlane(__float_as_int(mny),63));
  const float by1=__int_as_float(__builtin_amdgcn_readlane(__float_as_int(mxy),63));
  const float bz0=__int_as_float(__builtin_amdgcn_readlane(__float_as_int(mnz),63));
  const float bz1=__int_as_float(__builtin_amdgcn_readlane(__float_as_int(mxz),63));
  // hoisted: key constants (8192-orig)<<13 | slot  (>= 1<<13 > 0 always)
  u32 kb[8];
  {
    uint4 sp = *(const uint4*)&sidx[8*t];
    const u32 o0=sp.x&0xffffu, o1=sp.x>>16, o2=sp.y&0xffffu, o3=sp.y>>16;
    const u32 o4=sp.z&0xffffu, o5=sp.z>>16, o6=sp.w&0xffffu, o7=sp.w>>16;
    kb[0]=((8192u-o0)<<13)|(u32)(8*t+0); kb[1]=((8192u-o1)<<13)|(u32)(8*t+1);
    kb[2]=((8192u-o2)<<13)|(u32)(8*t+2); kb[3]=((8192u-o3)<<13)|(u32)(8*t+3);
    kb[4]=((8192u-o4)<<13)|(u32)(8*t+4); kb[5]=((8192u-o5)<<13)|(u32)(8*t+5);
    kb[6]=((8192u-o6)<<13)|(u32)(8*t+6); kb[7]=((8192u-o7)<<13)|(u32)(8*t+7);
  }

  f32x2 d[4];
  #pragma unroll
  for (int i=0;i<4;i++){ d[i][0]=__builtin_inff(); d[i][1]=__builtin_inff(); }
  u32 cached_kv = 0x7f800000u;           // +inf -> first step always updates
  u32 cached_ki = 0;

  float cx = xb[0], cy = xb[NPTS], cz = xb[2*NPTS];   // initial center = point 0
  float rx = 0.f, ry = 0.f, rz = 0.f;    // per-thread captured center (step == t)
  const int lane = t & 63, wv = t >> 6, l16 = lane & 15;
  for (int step=0; step<NS; step++){
    if (step == t){ rx = cx; ry = cy; rz = cz; }   // register capture, no vmem
    if (step==NS-1) break;
    // ---- wave-uniform prune test ----
    const float cval = __uint_as_float(cached_kv);
    float dxm = fmaxf(fmaxf(bx0-cx, cx-bx1), 0.f);
    float dym = fmaxf(fmaxf(by0-cy, cy-by1), 0.f);
    float dzm = fmaxf(fmaxf(bz0-cz, cz-bz1), 0.f);
    float lbs = ((dxm*dxm + dym*dym) + dzm*dzm) * 0.999f;   // conservative
    if (!(lbs > cval)){
      // ---- full update of this wave's 512 points (registers only) ----
      {
        #pragma clang fp contract(off)     // IEEE separate mul/add (numpy order)
        f32x2 cpx; cpx[0]=cx; cpx[1]=cx;
        f32x2 cpy; cpy[0]=cy; cpy[1]=cy;
        f32x2 cpz; cpz[0]=cz; cpz[1]=cz;
#define UPDP(pi, PX, PY, PZ) { \
        f32x2 dx = (PX) - cpx, dy = (PY) - cpy, dz = (PZ) - cpz; \
        f32x2 t1 = dx*dx; f32x2 t2 = dy*dy; f32x2 t3 = t1 + t2; \
        f32x2 t4 = dz*dz; f32x2 dd = t3 + t4; \
        d[pi] = __builtin_elementwise_min(dd, d[pi]); }
        UPDP(0, X0.lo, Y0.lo, Z0.lo)
        UPDP(1, X0.hi, Y0.hi, Z0.hi)
        UPDP(2, X1.lo, Y1.lo, Z1.lo)
        UPDP(3, X1.hi, Y1.hi, Z1.hi)
#undef UPDP
      }
      // value-only wave max
      f32x2 m0 = __builtin_elementwise_max(d[0], d[1]);
      f32x2 m1 = __builtin_elementwise_max(d[2], d[3]);
      f32x2 m2 = __builtin_elementwise_max(m0, m1);
      float bv = fmaxf(m2[0], m2[1]);
      RED6MAX(bv)                          // lane 63 valid
      const float wmax = __int_as_float(__builtin_amdgcn_readlane(__float_as_int(bv), 63));
      // matched-key recovery: parallel cndmask + umax tree (depth ~5)
      const u32 c0 = (d[0][0]==wmax)?kb[0]:0u;
      const u32 c1 = (d[0][1]==wmax)?kb[1]:0u;
      const u32 c2 = (d[1][0]==wmax)?kb[2]:0u;
      const u32 c3 = (d[1][1]==wmax)?kb[3]:0u;
      const u32 c4 = (d[2][0]==wmax)?kb[4]:0u;
      const u32 c5 = (d[2][1]==wmax)?kb[5]:0u;
      const u32 c6 = (d[3][0]==wmax)?kb[6]:0u;
      const u32 c7 = (d[3][1]==wmax)?kb[7]:0u;
      const u32 m01 = c0>c1?c0:c1, m23 = c2>c3?c2:c3;
      const u32 m45 = c4>c5?c4:c5, m67 = c6>c7?c6:c7;
      const u32 m03 = m01>m23?m01:m23, m47 = m45>m67?m45:m67;
      u32 ki = m03>m47?m03:m47;
      RED6UMAX(ki)                         // lane 63: max key = smallest orig
      cached_kv = __float_as_uint(wmax);
      cached_ki = (u32)__builtin_amdgcn_readlane((int)ki, 63);   // wave-uniform
    }
    const int p = step&1;                  // single barrier per step
    if (lane==0){ s_kv[p][wv]=cached_kv; s_ki[p][wv]=cached_ki; }
    __syncthreads();
    // ---- cross-wave: value-then-match within each 16-lane row; candidate
    //      coords prefetched CONCURRENTLY with the DPP reduce ----
    const u32 kv2 = s_kv[p][l16], ki2 = s_ki[p][l16];
    const int cslot = (int)(ki2 & 8191u);          // wave-l16 candidate slot
    const int cb2 = (cslot>>3)*28, ci = cslot&7;
    const float px = sc[cb2+ci], py = sc[cb2+8+ci], pz = sc[cb2+16+ci];
    const float kvf = __uint_as_float(kv2);
    float kvr = kvf;
    RED4MAXROW(kvr)                        // all lanes: row (=block) max value
    u32 mki = (kvf == kvr) ? ki2 : 0u;
    RED4UMAXROW(mki)                       // all lanes: winning key
    const u32 wk = (u32)__builtin_amdgcn_readfirstlane((int)mki);
    const int wwv = (int)((wk & 8191u) >> 9);      // winner wave = slot >> 9
    cx = __int_as_float(__builtin_amdgcn_readlane(__float_as_int(px), wwv));
    cy = __int_as_float(__builtin_amdgcn_readlane(__float_as_int(py), wwv));
    cz = __int_as_float(__builtin_amdgcn_readlane(__float_as_int(pz), wwv));
  }
  // ---- epilogue: coalesced center store (the loop's only global output) ----
  out_xyz[(size_t)(b*3+0)*NS + t] = rx;
  out_xyz[(size_t)(b*3+1)*NS + t] = ry;
  out_xyz[(size_t)(b*3+2)*NS + t] = rz;
}

// ---------------------------------------------------------- ball query ----
__global__ __launch_bounds__(256) void ballq_kernel(const float* __restrict__ xyz,
    const float* __restrict__ out_xyz, u16* __restrict__ gidx)
{
  const int gid = blockIdx.x*4 + (threadIdx.x>>6);
  const int lane = threadIdx.x & 63;
  const int b = gid >> 10, s = gid & (NS-1);
  const float* xb = xyz + (size_t)b*3*NPTS;
  const float cx = out_xyz[(size_t)(b*3+0)*NS+s];
  const float cy = out_xyz[(size_t)(b*3+1)*NS+s];
  const float cz = out_xyz[(size_t)(b*3+2)*NS+s];
  u16* out = gidx + (size_t)gid*KK;
  int cnt=0, first=-1;
  for (int base=0; base<NPTS; base+=64){
    const int pidx = base + lane;
    float d2 = d2_exact(cx,cy,cz, xb[pidx], xb[NPTS+pidx], xb[2*NPTS+pidx]);
    bool within = d2 < 0.04f;
    unsigned long long m = __ballot(within);
    if (m){
      if (first<0) first = base + (__ffsll(m)-1);
      int pos = cnt + (int)__popcll(m & ((1ull<<lane)-1ull));
      if (within && pos<KK) out[pos]=(u16)pidx;
      cnt += (int)__popcll(m);
      if (cnt>=KK) break;
    }
  }
  if (first<0) first=0;
  for (int posi = cnt + lane; posi < KK; posi += 64) out[posi]=(u16)first;
}

// --------------------------------------------------------------- MLP -----
#define MFMA16(A,B,C) __builtin_amdgcn_mfma_f32_16x16x32_f16(A,B,C,0,0,0)

template<int STAGE>
__global__ __launch_bounds__(256,2) void mlp_pass(
    const float* __restrict__ xyz, const float* __restrict__ feat,
    const float* __restrict__ out_xyz, const u16* __restrict__ gidx,
    const u16* __restrict__ fT,
    const u32* __restrict__ Wf1, const u32* __restrict__ Wf2, const u32* __restrict__ Wf3,
    const float* __restrict__ W0raw,
    const float* __restrict__ affine, float* __restrict__ stats, u32* __restrict__ outMM)
{
  constexpr int TCO = (STAGE==2)?128:64;
  __shared__ alignas(16) u32 Xs[64*48];          // 12 KB
  __shared__ float bins[2*TCO];
  __shared__ u32 mm[(STAGE==2)? 2*4*128 : 4];    // double-buffered cross-wave panel

  const int t = threadIdx.x;
  const int lane = t&63, w = t>>6, n = lane&15, q = lane>>4;
  const int j = t>>2, q4 = t&3;
  const int colbase = (w*16+n)*48;
  const int u_   = blockIdx.x;                   // XCD-affinity swizzle
  const int slot = u_ & 7, rr = u_ >> 3;
  const int bb   = slot*2 + (rr>>7);
  const int inner= rr & 127;
  if (t < 2*TCO) bins[t]=0.f;
  __syncthreads();

  #pragma unroll 1
  for (int ch=0; ch<4; ch++){
    const int ssb = (bb*128 + inner)*256 + ch*64;
    const int ss = ssb + j;
    const int s = (ss >> 5) & (NS-1);
    const int g = ((int)gidx[ss]) & (NPTS-1);
    {
      u32* Xrow = &Xs[j*48];
      if (q4==3){
        const float* xb = xyz + (size_t)bb*3*NPTS;
        float dx=__fsub_rn(xb[g],        out_xyz[(size_t)(bb*3+0)*NS+s]);
        float dy=__fsub_rn(xb[NPTS+g],   out_xyz[(size_t)(bb*3+1)*NS+s]);
        float dz=__fsub_rn(xb[2*NPTS+g], out_xyz[(size_t)(bb*3+2)*NS+s]);
        Xrow[32]=packh(dx,dy); Xrow[33]=packh(dz,0.f);
      }
      #pragma unroll
      for (int i=34+q4;i<48;i+=4) Xrow[i]=0;
    }
    const u16* fr;
    {
      const int gl = ((int)gidx[ssb + w*16 + n]) & (NPTS-1);
      fr = fT + ((size_t)bb*NPTS + gl)*64;
    }
    // ---- layer 1 ----
    f32x4 acc[4];
    #pragma unroll
    for (int tc=0;tc<4;tc++) acc[tc]=zero4();
    #pragma unroll
    for (int kc=0;kc<2;kc++){
      f16x8 Bf = *(const f16x8*)(fr + kc*32 + q*8);
      #pragma unroll
      for (int tc=0;tc<4;tc++){
        f16x8 Af = *(const f16x8*)&Wf1[((tc*2+kc)*64+lane)*4];
        acc[tc] = MFMA16(Af,Bf,acc[tc]);
      }
    }
    {  // xyz chunk
      f16x8 Bf = *(const f16x8*)&Xs[colbase + 32 + q*4];
      #pragma unroll
      for (int tc=0;tc<4;tc++){
        f16x8 Af = zero8h();
        if (q==0){
          const int row = tc*16+n;
          Af[0]=(_Float16)W0raw[row*67+0];
          Af[1]=(_Float16)W0raw[row*67+1];
          Af[2]=(_Float16)W0raw[row*67+2];
        }
        acc[tc] = MFMA16(Af,Bf,acc[tc]);
      }
    }

    if constexpr (STAGE==0){
      #pragma unroll
      for (int tc=0;tc<4;tc++){
        #pragma unroll
        for (int r=0;r<4;r++){
          float s1=acc[tc][r], s2=__fmul_rn(s1,s1);
          #pragma unroll
          for (int off=1;off<16;off<<=1){ s1+=__shfl_xor(s1,off); s2+=__shfl_xor(s2,off); }
          if (n==0){ const int c=tc*16+q*4+r;
            atomicAdd(&bins[c], s1); atomicAdd(&bins[TCO+c], s2); }
        }
      }
    } else {
      #pragma unroll
      for (int tc=0;tc<4;tc++){
        const f32x4 sc4 = *(const f32x4*)&affine[tc*16+q*4];
        const f32x4 sh4 = *(const f32x4*)&affine[128+tc*16+q*4];
        Xs[colbase + tc*8+q*2]   = packh(fmaxf(fmaf(acc[tc][0],sc4[0],sh4[0]),0.f),
                                         fmaxf(fmaf(acc[tc][1],sc4[1],sh4[1]),0.f));
        Xs[colbase + tc*8+q*2+1] = packh(fmaxf(fmaf(acc[tc][2],sc4[2],sh4[2]),0.f),
                                         fmaxf(fmaf(acc[tc][3],sc4[3],sh4[3]),0.f));
      }
      // ---- layer 2 ----
      f32x4 acc2[4];
      #pragma unroll
      for (int tc=0;tc<4;tc++) acc2[tc]=zero4();
      #pragma unroll
      for (int kc=0;kc<2;kc++){
        f16x8 Bf = *(const f16x8*)&Xs[colbase + kc*16 + q*4];
        #pragma unroll
        for (int tc=0;tc<4;tc++){
          f16x8 Af = *(const f16x8*)&Wf2[((tc*2+kc)*64+lane)*4];
          acc2[tc] = MFMA16(Af,Bf,acc2[tc]);
        }
      }
      if constexpr (STAGE==1){
        #pragma unroll
        for (int tc=0;tc<4;tc++){
          #pragma unroll
          for (int r=0;r<4;r++){
            float s1=acc2[tc][r], s2=__fmul_rn(s1,s1);
            #pragma unroll
            for (int off=1;off<16;off<<=1){ s1+=__shfl_xor(s1,off); s2+=__shfl_xor(s2,off); }
            if (n==0){ const int c=tc*16+q*4+r;
              atomicAdd(&bins[c], s1); atomicAdd(&bins[TCO+c], s2); }
          }
        }
      } else {
        #pragma unroll
        for (int tc=0;tc<4;tc++){
          const f32x4 sc4 = *(const f32x4*)&affine[256+tc*16+q*4];
          const f32x4 sh4 = *(const f32x4*)&affine[256+128+tc*16+q*4];
          Xs[colbase + tc*8+q*2]   = packh(fmaxf(fmaf(acc2[tc][0],sc4[0],sh4[0]),0.f),
                                           fmaxf(fmaf(acc2[tc][1],sc4[1],sh4[1]),0.f));
          Xs[colbase + tc*8+q*2+1] = packh(fmaxf(fmaf(acc2[tc][2],sc4[2],sh4[2]),0.f),
                                           fmaxf(fmaf(acc2[tc][3],sc4[3],sh4[3]),0.f));
        }
        // ---- layer 3 ----
        f32x4 acc3[8];
        #pragma unroll
        for (int tc=0;tc<8;tc++) acc3[tc]=zero4();
        #pragma unroll
        for (int kc=0;kc<2;kc++){
          f16x8 Bf = *(const f16x8*)&Xs[colbase + kc*16 + q*4];
          #pragma unroll
          for (int tc=0;tc<8;tc++){
            f16x8 Af = *(const f16x8*)&Wf3[((tc*2+kc)*64+lane)*4];
            acc3[tc] = MFMA16(Af,Bf,acc3[tc]);
          }
        }
        u32* mmb = &mm[(ch&1)*512];
        #pragma unroll
        for (int tc=0;tc<8;tc++){
          #pragma unroll
          for (int r=0;r<4;r++){
            float y=acc3[tc][r];
            float s1=y, s2=__fmul_rn(y,y);
            u32 pm = packh(y, -y);
            #pragma unroll
            for (int off=1;off<16;off<<=1){
              s1+=__shfl_xor(s1,off); s2+=__shfl_xor(s2,off);
              u32 o = (u32)__shfl_xor((int)pm,off);
              pm = asU32(__builtin_elementwise_max(asH2(pm), asH2(o)));
            }
            if (n==0){ const int c=tc*16+q*4+r;
              atomicAdd(&bins[c], s1); atomicAdd(&bins[128+c], s2);
              mmb[w*128+c]=pm; }
          }
        }
        __syncthreads();
        {
          const int c = t&127, gg = t>>7;
          u32 a = mmb[(2*gg)*128+c], b2 = mmb[(2*gg+1)*128+c];
          h2v hm = __builtin_elementwise_max(asH2(a), asH2(b2));
          const int s0 = inner*8 + ch*2 + gg;
          outMM[((size_t)bb*128+c)*NS + s0] = packh((float)hm[0], -(float)hm[1]);
        }
      }
    }
  }

  __syncthreads();
  if (t < TCO){
    atomicAdd(&stats[STAGE*256 + 2*t],   bins[t]);
    atomicAdd(&stats[STAGE*256 + 2*t+1], bins[TCO+t]);
  }
}

// ----------------------------------------------------------- finalize ----
__global__ void finalize_kernel(const float* __restrict__ st, float* __restrict__ af,
                                const float* __restrict__ gamma, const float* __restrict__ beta, int C)
{
  int c = threadIdx.x;
  if (c < C){
    float mean = st[2*c] * (1.f/524288.f);
    float var  = fmaxf(st[2*c+1] * (1.f/524288.f) - mean*mean, 0.f);
    float rstd = 1.f / sqrtf(var + 1e-5f);
    float sc = rstd * gamma[c];
    af[c]     = sc;
    af[128+c] = beta[c] - mean*sc;
  }
}

// -------------------------------------------------------------- apply ----
__global__ void apply_kernel(const float* __restrict__ affine, float* __restrict__ outF)
{
  const int i = blockIdx.x*256 + threadIdx.x;
  const int c = (i >> 10) & 127;
  u32 v = ((const u32*)outF)[i];
  h2v h = asH2(v);
  float sc = affine[512+c], sh = affine[512+128+c];
  float cand = (sc > 0.f) ? (float)h[0] : (float)h[1];
  outF[i] = fmaxf(fmaf(cand, sc, sh), 0.f);
}

// ------------------------------------------------------------- launch ----
extern "C" void kernel_launch(void* const* d_in, const int* in_sizes, int n_in,
                              void* d_out, int out_size, void* d_ws, size_t ws_size,
                              hipStream_t stream)
{
  (void)in_sizes; (void)n_in; (void)out_size; (void)ws_size;
  const float* xyz  = (const float*)d_in[0];
  const float* feat = (const float*)d_in[1];
  const float* W0 = (const float*)d_in[2];
  const float* g0 = (const float*)d_in[3];
  const float* b0 = (const float*)d_in[4];
  const float* W1 = (const float*)d_in[5];
  const float* g1 = (const float*)d_in[6];
  const float* b1 = (const float*)d_in[7];
  const float* W2 = (const float*)d_in[8];
  const float* g2 = (const float*)d_in[9];
  const float* b2 = (const float*)d_in[10];

  char* ws = (char*)d_ws;                       // 17,864,704 B (proven R14)
  u16*   fT     = (u16*)  (ws + 0);             // 16,777,216 B
  u16*   gidx   = (u16*)  (ws + 16777216);      //  1,048,576 B
  u32*   Wf1    = (u32*)  (ws + 17825792);      //      8192 B
  u32*   Wf2    = (u32*)  (ws + 17833984);      //      8192 B
  u32*   Wf3    = (u32*)  (ws + 17842176);      //     16384 B
  float* stats  = (float*)(ws + 17858560);      //      3072 B
  float* affine = (float*)(ws + 17861632);      //      3072 B

  float* out_xyz  = (float*)d_out;                         // (16,3,1024) f32
  float* out_feat = (float*)d_out + (size_t)NB*3*NS;       // (16,128,1024) f32

  prep_kernel<<<1,256,0,stream>>>(W0,W1,W2,Wf1,Wf2,Wf3,stats);
  transpose_kernel<<<2048,256,0,stream>>>(feat, (u32*)fT);
  fps_kernel<<<NB,1024,0,stream>>>(xyz, out_xyz);
  ballq_kernel<<<NB*NS/4,256,0,stream>>>(xyz, out_xyz, gidx);

  mlp_pass<0><<<NSAMP/256,256,0,stream>>>(xyz,feat,out_xyz,gidx,fT,Wf1,Wf2,Wf3,W0,affine,stats,(u32*)out_feat);
  finalize_kernel<<<1,128,0,stream>>>(stats,     affine,     g0,b0, 64);
  mlp_pass<1><<<NSAMP/256,256,0,stream>>>(xyz,feat,out_xyz,gidx,fT,Wf1,Wf2,Wf3,W0,affine,stats,(u32*)out_feat);
  finalize_kernel<<<1,128,0,stream>>>(stats+256, affine+256, g1,b1, 64);
  mlp_pass<2><<<NSAMP/256,256,0,stream>>>(xyz,feat,out_xyz,gidx,fT,Wf1,Wf2,Wf3,W0,affine,stats,(u32*)out_feat);
  finalize_kernel<<<1,128,0,stream>>>(stats+512, affine+512, g2,b2, 128);
  apply_kernel<<<(NB*128*NS)/256,256,0,stream>>>(affine, out_feat);
}

// Round 13
// 1572.876 us; speedup vs baseline: 1.0840x; 1.0840x over previous
//
#include <hip/hip_runtime.h>

// PointNetSAModule on MI355X (gfx950).
// B=16, N=8192, CIN=64, S=1024, K=32, radius=0.2, MLP 67->64->64->128, eps=1e-5.
// Inputs/outputs float32. ws >= 17.9 MB proven (R14).
//
// R22 resubmit #6 (six consecutive GPU-acquisition timeouts, no verdict):
//  * fps byte-exact R19 (best measured: 900us, conflicts 62K).
//    R21's candidate-prefetch is dead: scattered 16-slot LDS reads drove
//    SQ_LDS_BANK_CONFLICT 62K -> 2.25M and fps 900 -> 1012us.
//  * finalize_kernel launches removed: each consumer recomputes the affine
//    from stats inline into LDS (identical inputs + op order -> identical
//    values). mlp_pass<1> computes layer0 affine; mlp_pass<2> computes
//    layer0+layer1; apply computes layer2. Saves 3 dispatches + gaps.

typedef unsigned short u16;
typedef unsigned int   u32;
typedef unsigned long long u64;

#define NB    16
#define NPTS  8192
#define CINF  64
#define NS    1024
#define KK    32
#define NSAMP (NB*NS*KK)   // 524288

typedef _Float16 h2v   __attribute__((ext_vector_type(2)));
typedef _Float16 f16x8 __attribute__((ext_vector_type(8)));
typedef float    f32x4 __attribute__((ext_vector_type(4)));
typedef float    f32x2 __attribute__((ext_vector_type(2)));

static __device__ __forceinline__ h2v asH2(u32 x){ union{u32 u; h2v h;} v; v.u=x; return v.h; }
static __device__ __forceinline__ u32 asU32(h2v h){ union{u32 u; h2v h;} v; v.h=h; return v.u; }
static __device__ __forceinline__ u32 packh(float lo, float hi){
  union{ _Float16 h[2]; u32 u; } v;
  v.h[0]=(_Float16)lo; v.h[1]=(_Float16)hi; return v.u;
}
static __device__ __forceinline__ u16 f16b(float z){
  union{ _Float16 h; u16 s; } v; v.h=(_Float16)z; return v.s;
}
static __device__ __forceinline__ f32x4 zero4(){ f32x4 z; z[0]=0.f;z[1]=0.f;z[2]=0.f;z[3]=0.f; return z; }
static __device__ __forceinline__ f16x8 zero8h(){
  f16x8 z;
  #pragma unroll
  for (int i=0;i<8;i++) z[i]=(_Float16)0.f;
  return z;
}

// exact-order d^2, matching numpy f32: (dx*dx + dy*dy) + dz*dz, no FMA contraction
static __device__ __forceinline__ float d2_exact(float ax,float ay,float az,float bx,float by,float bz){
  float dx=__fsub_rn(ax,bx), dy=__fsub_rn(ay,by), dz=__fsub_rn(az,bz);
  return __fadd_rn(__fadd_rn(__fmul_rn(dx,dx),__fmul_rn(dy,dy)),__fmul_rn(dz,dz));
}

// DPP helpers (VALU pipe)
template<int CTRL, int RMASK>
static __device__ __forceinline__ float dppfmax1(float v){
  int o = __builtin_amdgcn_update_dpp(__float_as_int(v), __float_as_int(v),
                                      CTRL, RMASK, 0xf, false);
  return fmaxf(v, __int_as_float(o));
}
template<int CTRL, int RMASK>
static __device__ __forceinline__ float dppfmin1(float v){
  int o = __builtin_amdgcn_update_dpp(__float_as_int(v), __float_as_int(v),
                                      CTRL, RMASK, 0xf, false);
  return fminf(v, __int_as_float(o));
}
template<int CTRL, int RMASK>
static __device__ __forceinline__ u32 dppumax1(u32 v){
  u32 o = (u32)__builtin_amdgcn_update_dpp((int)v, (int)v, CTRL, RMASK, 0xf, false);
  return v > o ? v : o;
}
#define RED6MAX(v) { v=dppfmax1<0xB1,0xf>(v); v=dppfmax1<0x4E,0xf>(v); v=dppfmax1<0x141,0xf>(v); \
                     v=dppfmax1<0x140,0xf>(v); v=dppfmax1<0x142,0xa>(v); v=dppfmax1<0x143,0xc>(v); }
#define RED6MIN(v) { v=dppfmin1<0xB1,0xf>(v); v=dppfmin1<0x4E,0xf>(v); v=dppfmin1<0x141,0xf>(v); \
                     v=dppfmin1<0x140,0xf>(v); v=dppfmin1<0x142,0xa>(v); v=dppfmin1<0x143,0xc>(v); }
#define RED6UMAX(v) { v=dppumax1<0xB1,0xf>(v); v=dppumax1<0x4E,0xf>(v); v=dppumax1<0x141,0xf>(v); \
                      v=dppumax1<0x140,0xf>(v); v=dppumax1<0x142,0xa>(v); v=dppumax1<0x143,0xc>(v); }
// 4-level (within-row-of-16) full reduce: every lane of each 16-lane row
// ends holding the row max.
#define RED4MAXROW(v) { v=dppfmax1<0xB1,0xf>(v); v=dppfmax1<0x4E,0xf>(v); \
                        v=dppfmax1<0x141,0xf>(v); v=dppfmax1<0x140,0xf>(v); }
#define RED4UMAXROW(v) { v=dppumax1<0xB1,0xf>(v); v=dppumax1<0x4E,0xf>(v); \
                         v=dppumax1<0x141,0xf>(v); v=dppumax1<0x140,0xf>(v); }

// ---------------------------------------------------------------- prep ----
__global__ void prep_kernel(const float* __restrict__ W0, const float* __restrict__ W1,
                            const float* __restrict__ W2,
                            u32* __restrict__ Wf1, u32* __restrict__ Wf2, u32* __restrict__ Wf3,
                            float* __restrict__ stats)
{
  const int t = threadIdx.x;
  for (int i=t;i<768;i+=256) stats[i]=0.f;
  for (int i=t;i<2048;i+=256){           // L1: 4 tiles x 2 chunks (feat cols only)
    int d=i&3, lane=(i>>2)&63, kc=(i>>8)&1, tc=i>>9;
    int row=tc*16+(lane&15), k0=kc*32+(lane>>4)*8+2*d;
    Wf1[i]=packh(W0[row*67+3+k0], W0[row*67+4+k0]);
  }
  for (int i=t;i<2048;i+=256){           // L2
    int d=i&3, lane=(i>>2)&63, kc=(i>>8)&1, tc=i>>9;
    int row=tc*16+(lane&15), k0=kc*32+(lane>>4)*8+2*d;
    Wf2[i]=packh(W1[row*64+k0], W1[row*64+k0+1]);
  }
  for (int i=t;i<4096;i+=256){           // L3
    int d=i&3, lane=(i>>2)&63, kc=(i>>8)&1, tc=i>>9;
    int row=tc*16+(lane&15), k0=kc*32+(lane>>4)*8+2*d;
    Wf3[i]=packh(W2[row*64+k0], W2[row*64+k0+1]);
  }
}

// ----------------------------------------------------- feat transpose ----
__global__ __launch_bounds__(256) void transpose_kernel(const float* __restrict__ feat,
                                                        u32* __restrict__ fT32)
{
  __shared__ u16 tile[64][65];
  const int b  = blockIdx.x >> 7;
  const int n0 = (blockIdx.x & 127) << 6;
  const int t = threadIdx.x;
  const int ln = t & 63, lc = t >> 6;
  #pragma unroll
  for (int cc=0; cc<64; cc+=4){
    const int c = cc + lc;
    tile[c][ln] = f16b(feat[((size_t)b*64 + c)*NPTS + n0 + ln]);
  }
  __syncthreads();
  #pragma unroll
  for (int i=0;i<8;i++){
    const int idx = t*8 + i;
    const int row = idx >> 5, dw = idx & 31;
    u32 pair = (u32)tile[2*dw][row] | ((u32)tile[2*dw+1][row] << 16);
    fT32[((size_t)b*NPTS + n0 + row)*32 + dw] = pair;
  }
}

// ----------------------------------------------------------------- FPS ----
// one block per batch; 1024 threads. Morton sort -> wave-compact regions,
// wave bbox prune (no-op skip). Update path entirely in registers; tail is
// value-then-match DPP over 16 wave records + one uniform broadcast LDS
// read of the winner's coords from sc[]. NO global ops inside the step loop:
// thread t captures the step-t center in registers; coalesced epilogue store.
__global__ __launch_bounds__(1024,1) void fps_kernel(const float* __restrict__ xyz,
    float* __restrict__ out_xyz)
{
  __shared__ float sc[1024*28];            // sorted coords: 8/thread x8|y8|z8|pad4
  __shared__ u16  sidx[NPTS];              // sorted slot -> orig idx
  __shared__ u32  hcnt[64], hoff[64];
  __shared__ u32  s_kv[2][16], s_ki[2][16];
  const int b = blockIdx.x, t = threadIdx.x;
  const float* xb = xyz + (size_t)b*3*NPTS;
  if (t<64) hcnt[t]=0;
  __syncthreads();
  // ---- pass 1: load (coalesced), Morton cell, histogram ----
  float lx[8], ly[8], lz[8]; int lcell[8];
  #pragma unroll
  for (int i=0;i<8;i++){
    const int idx = t + 1024*i;
    float x=xb[idx], y=xb[NPTS+idx], z=xb[2*NPTS+idx];
    lx[i]=x; ly[i]=y; lz[i]=z;
    int ix=(int)(x*4.f); ix = ix<0?0:(ix>3?3:ix);
    int iy=(int)(y*4.f); iy = iy<0?0:(iy>3?3:iy);
    int iz=(int)(z*4.f); iz = iz<0?0:(iz>3?3:iz);
    int m = (ix&1)|((iy&1)<<1)|((iz&1)<<2)|((ix&2)<<2)|((iy&2)<<3)|((iz&2)<<4);
    lcell[i]=m;
    atomicAdd(&hcnt[m],1u);
  }
  __syncthreads();
  if (t==0){ u32 s=0; for (int c=0;c<64;c++){ hoff[c]=s; s+=hcnt[c]; } }
  __syncthreads();
  // ---- scatter into sorted LDS layout ----
  #pragma unroll
  for (int i=0;i<8;i++){
    u32 pos = atomicAdd(&hoff[lcell[i]],1u);
    const int rb=(int)(pos>>3)*28+(int)(pos&7);
    sc[rb]=lx[i]; sc[rb+8]=ly[i]; sc[rb+16]=lz[i];
    sidx[pos]=(u16)(t+1024*i);
  }
  __syncthreads();
  // ---- pull this thread's 8 sorted points into registers; sc[] remains
  //      valid for the tail's winner-coord broadcast read ----
  const int tb = t*28;
  const f32x4 X0=*(const f32x4*)&sc[tb],   X1=*(const f32x4*)&sc[tb+4];
  const f32x4 Y0=*(const f32x4*)&sc[tb+8], Y1=*(const f32x4*)&sc[tb+12];
  const f32x4 Z0=*(const f32x4*)&sc[tb+16],Z1=*(const f32x4*)&sc[tb+20];
  // ---- wave bbox ----
  float mnx,mxx,mny,mxy,mnz,mxz;
  {
    mnx=mxx=X0[0]; mny=mxy=Y0[0]; mnz=mxz=Z0[0];
    #pragma unroll
    for (int i=0;i<4;i++){
      mnx=fminf(mnx,fminf(X0[i],X1[i])); mxx=fmaxf(mxx,fmaxf(X0[i],X1[i]));
      mny=fminf(mny,fminf(Y0[i],Y1[i])); mxy=fmaxf(mxy,fmaxf(Y0[i],Y1[i]));
      mnz=fminf(mnz,fminf(Z0[i],Z1[i])); mxz=fmaxf(mxz,fmaxf(Z0[i],Z1[i]));
    }
  }
  RED6MIN(mnx) RED6MIN(mny) RED6MIN(mnz)
  RED6MAX(mxx) RED6MAX(mxy) RED6MAX(mxz)
  const float bx0=__int_as_float(__builtin_amdgcn_readlane(__float_as_int(mnx),63));
  const float bx1=__int_as_float(__builtin_amdgcn_readlane(__float_as_int(mxx),63));
  const float by0=__int_as_float(__builtin_amdgcn_readlane(__float_as_int(mny),63));
  const float by1=__int_as_float(__builtin_amdgcn_readlane(__float_as_int(mxy),63));
  const float bz0=__int_as_float(__builtin_amdgcn_readlane(__float_as_int(mnz),63));
  const float bz1=__int_as_float(__builtin_amdgcn_readlane(__float_as_int(mxz),63));
  // hoisted: key constants (8192-orig)<<13 | slot  (>= 1<<13 > 0 always)
  u32 kb[8];
  {
    uint4 sp = *(const uint4*)&sidx[8*t];
    const u32 o0=sp.x&0xffffu, o1=sp.x>>16, o2=sp.y&0xffffu, o3=sp.y>>16;
    const u32 o4=sp.z&0xffffu, o5=sp.z>>16, o6=sp.w&0xffffu, o7=sp.w>>16;
    kb[0]=((8192u-o0)<<13)|(u32)(8*t+0); kb[1]=((8192u-o1)<<13)|(u32)(8*t+1);
    kb[2]=((8192u-o2)<<13)|(u32)(8*t+2); kb[3]=((8192u-o3)<<13)|(u32)(8*t+3);
    kb[4]=((8192u-o4)<<13)|(u32)(8*t+4); kb[5]=((8192u-o5)<<13)|(u32)(8*t+5);
    kb[6]=((8192u-o6)<<13)|(u32)(8*t+6); kb[7]=((8192u-o7)<<13)|(u32)(8*t+7);
  }

  f32x2 d[4];
  #pragma unroll
  for (int i=0;i<4;i++){ d[i][0]=__builtin_inff(); d[i][1]=__builtin_inff(); }
  u32 cached_kv = 0x7f800000u;           // +inf -> first step always updates
  u32 cached_ki = 0;

  float cx = xb[0], cy = xb[NPTS], cz = xb[2*NPTS];   // initial center = point 0
  float rx = 0.f, ry = 0.f, rz = 0.f;    // per-thread captured center (step == t)
  const int lane = t & 63, wv = t >> 6, l16 = lane & 15;
  for (int step=0; step<NS; step++){
    if (step == t){ rx = cx; ry = cy; rz = cz; }   // register capture, no vmem
    if (step==NS-1) break;
    // ---- wave-uniform prune test ----
    const float cval = __uint_as_float(cached_kv);
    float dxm = fmaxf(fmaxf(bx0-cx, cx-bx1), 0.f);
    float dym = fmaxf(fmaxf(by0-cy, cy-by1), 0.f);
    float dzm = fmaxf(fmaxf(bz0-cz, cz-bz1), 0.f);
    float lbs = ((dxm*dxm + dym*dym) + dzm*dzm) * 0.999f;   // conservative
    if (!(lbs > cval)){
      // ---- full update of this wave's 512 points (registers only) ----
      {
        #pragma clang fp contract(off)     // IEEE separate mul/add (numpy order)
        f32x2 cpx; cpx[0]=cx; cpx[1]=cx;
        f32x2 cpy; cpy[0]=cy; cpy[1]=cy;
        f32x2 cpz; cpz[0]=cz; cpz[1]=cz;
#define UPDP(pi, PX, PY, PZ) { \
        f32x2 dx = (PX) - cpx, dy = (PY) - cpy, dz = (PZ) - cpz; \
        f32x2 t1 = dx*dx; f32x2 t2 = dy*dy; f32x2 t3 = t1 + t2; \
        f32x2 t4 = dz*dz; f32x2 dd = t3 + t4; \
        d[pi] = __builtin_elementwise_min(dd, d[pi]); }
        UPDP(0, X0.lo, Y0.lo, Z0.lo)
        UPDP(1, X0.hi, Y0.hi, Z0.hi)
        UPDP(2, X1.lo, Y1.lo, Z1.lo)
        UPDP(3, X1.hi, Y1.hi, Z1.hi)
#undef UPDP
      }
      // value-only wave max
      f32x2 m0 = __builtin_elementwise_max(d[0], d[1]);
      f32x2 m1 = __builtin_elementwise_max(d[2], d[3]);
      f32x2 m2 = __builtin_elementwise_max(m0, m1);
      float bv = fmaxf(m2[0], m2[1]);
      RED6MAX(bv)                          // lane 63 valid
      const float wmax = __int_as_float(__builtin_amdgcn_readlane(__float_as_int(bv), 63));
      // matched-key recovery: parallel cndmask + umax tree (depth ~5)
      const u32 c0 = (d[0][0]==wmax)?kb[0]:0u;
      const u32 c1 = (d[0][1]==wmax)?kb[1]:0u;
      const u32 c2 = (d[1][0]==wmax)?kb[2]:0u;
      const u32 c3 = (d[1][1]==wmax)?kb[3]:0u;
      const u32 c4 = (d[2][0]==wmax)?kb[4]:0u;
      const u32 c5 = (d[2][1]==wmax)?kb[5]:0u;
      const u32 c6 = (d[3][0]==wmax)?kb[6]:0u;
      const u32 c7 = (d[3][1]==wmax)?kb[7]:0u;
      const u32 m01 = c0>c1?c0:c1, m23 = c2>c3?c2:c3;
      const u32 m45 = c4>c5?c4:c5, m67 = c6>c7?c6:c7;
      const u32 m03 = m01>m23?m01:m23, m47 = m45>m67?m45:m67;
      u32 ki = m03>m47?m03:m47;
      RED6UMAX(ki)                         // lane 63: max key = smallest orig
      cached_kv = __float_as_uint(wmax);
      cached_ki = (u32)__builtin_amdgcn_readlane((int)ki, 63);   // wave-uniform
    }
    const int p = step&1;                  // single barrier per step
    if (lane==0){ s_kv[p][wv]=cached_kv; s_ki[p][wv]=cached_ki; }
    __syncthreads();
    // ---- cross-wave: value-then-match within each 16-lane row ----
    const u32 kv2 = s_kv[p][l16], ki2 = s_ki[p][l16];
    const float kvf = __uint_as_float(kv2);
    float kvr = kvf;
    RED4MAXROW(kvr)                        // all lanes: row (=block) max value
    u32 mki = (kvf == kvr) ? ki2 : 0u;
    RED4UMAXROW(mki)                       // all lanes: winning key
    const int wslot = (int)((u32)__builtin_amdgcn_readfirstlane((int)mki) & 8191u);
    const int wb2 = (wslot>>3)*28, wi = wslot&7;
    cx = sc[wb2+wi]; cy = sc[wb2+8+wi]; cz = sc[wb2+16+wi];
  }
  // ---- epilogue: coalesced center store (the loop's only global output) ----
  out_xyz[(size_t)(b*3+0)*NS + t] = rx;
  out_xyz[(size_t)(b*3+1)*NS + t] = ry;
  out_xyz[(size_t)(b*3+2)*NS + t] = rz;
}

// ---------------------------------------------------------- ball query ----
__global__ __launch_bounds__(256) void ballq_kernel(const float* __restrict__ xyz,
    const float* __restrict__ out_xyz, u16* __restrict__ gidx)
{
  const int gid = blockIdx.x*4 + (threadIdx.x>>6);
  const int lane = threadIdx.x & 63;
  const int b = gid >> 10, s = gid & (NS-1);
  const float* xb = xyz + (size_t)b*3*NPTS;
  const float cx = out_xyz[(size_t)(b*3+0)*NS+s];
  const float cy = out_xyz[(size_t)(b*3+1)*NS+s];
  const float cz = out_xyz[(size_t)(b*3+2)*NS+s];
  u16* out = gidx + (size_t)gid*KK;
  int cnt=0, first=-1;
  for (int base=0; base<NPTS; base+=64){
    const int pidx = base + lane;
    float d2 = d2_exact(cx,cy,cz, xb[pidx], xb[NPTS+pidx], xb[2*NPTS+pidx]);
    bool within = d2 < 0.04f;
    unsigned long long m = __ballot(within);
    if (m){
      if (first<0) first = base + (__ffsll(m)-1);
      int pos = cnt + (int)__popcll(m & ((1ull<<lane)-1ull));
      if (within && pos<KK) out[pos]=(u16)pidx;
      cnt += (int)__popcll(m);
      if (cnt>=KK) break;
    }
  }
  if (first<0) first=0;
  for (int posi = cnt + lane; posi < KK; posi += 64) out[posi]=(u16)first;
}

// --------------------------------------------------------------- MLP -----
#define MFMA16(A,B,C) __builtin_amdgcn_mfma_f32_16x16x32_f16(A,B,C,0,0,0)

// STAGE 0: stats of layer1.  STAGE 1: layer1(affine0)+stats of layer2.
// STAGE 2: layer1+layer2(affine0/1)+layer3+stats+minmax panel.
// Affines are recomputed inline per block from stats (identical inputs and
// op order as the old finalize_kernel -> identical values in every block).
template<int STAGE>
__global__ __launch_bounds__(256,2) void mlp_pass(
    const float* __restrict__ xyz, const float* __restrict__ feat,
    const float* __restrict__ out_xyz, const u16* __restrict__ gidx,
    const u16* __restrict__ fT,
    const u32* __restrict__ Wf1, const u32* __restrict__ Wf2, const u32* __restrict__ Wf3,
    const float* __restrict__ W0raw,
    const float* __restrict__ gA, const float* __restrict__ bA,
    const float* __restrict__ gB, const float* __restrict__ bB,
    float* __restrict__ stats, u32* __restrict__ outMM)
{
  constexpr int TCO = (STAGE==2)?128:64;
  __shared__ alignas(16) u32 Xs[64*48];          // 12 KB
  __shared__ float bins[2*TCO];
  __shared__ u32 mm[(STAGE==2)? 2*4*128 : 4];    // double-buffered cross-wave panel
  __shared__ float aff[(STAGE>=1)? 448 : 4];     // inline affine (layout = old global)

  const int t = threadIdx.x;
  const int lane = t&63, w = t>>6, n = lane&15, q = lane>>4;
  const int j = t>>2, q4 = t&3;
  const int colbase = (w*16+n)*48;
  const int u_   = blockIdx.x;                   // XCD-affinity swizzle
  const int slot = u_ & 7, rr = u_ >> 3;
  const int bb   = slot*2 + (rr>>7);
  const int inner= rr & 127;
  if (t < 2*TCO) bins[t]=0.f;
  if constexpr (STAGE>=1){
    if (t < 64){                                 // layer0 affine from stats seg 0
      const float mean = stats[2*t] * (1.f/524288.f);
      const float var  = fmaxf(stats[2*t+1] * (1.f/524288.f) - mean*mean, 0.f);
      const float rstd = 1.f / sqrtf(var + 1e-5f);
      const float s0 = rstd * gA[t];
      aff[t] = s0; aff[128+t] = bA[t] - mean*s0;
    }
  }
  if constexpr (STAGE==2){
    if (t >= 64 && t < 128){                     // layer1 affine from stats seg 1
      const int c = t - 64;
      const float mean = stats[256+2*c] * (1.f/524288.f);
      const float var  = fmaxf(stats[256+2*c+1] * (1.f/524288.f) - mean*mean, 0.f);
      const float rstd = 1.f / sqrtf(var + 1e-5f);
      const float s1 = rstd * gB[c];
      aff[256+c] = s1; aff[384+c] = bB[c] - mean*s1;
    }
  }
  __syncthreads();

  #pragma unroll 1
  for (int ch=0; ch<4; ch++){
    const int ssb = (bb*128 + inner)*256 + ch*64;
    const int ss = ssb + j;
    const int s = (ss >> 5) & (NS-1);
    const int g = ((int)gidx[ss]) & (NPTS-1);
    {
      u32* Xrow = &Xs[j*48];
      if (q4==3){
        const float* xb = xyz + (size_t)bb*3*NPTS;
        float dx=__fsub_rn(xb[g],        out_xyz[(size_t)(bb*3+0)*NS+s]);
        float dy=__fsub_rn(xb[NPTS+g],   out_xyz[(size_t)(bb*3+1)*NS+s]);
        float dz=__fsub_rn(xb[2*NPTS+g], out_xyz[(size_t)(bb*3+2)*NS+s]);
        Xrow[32]=packh(dx,dy); Xrow[33]=packh(dz,0.f);
      }
      #pragma unroll
      for (int i=34+q4;i<48;i+=4) Xrow[i]=0;
    }
    const u16* fr;
    {
      const int gl = ((int)gidx[ssb + w*16 + n]) & (NPTS-1);
      fr = fT + ((size_t)bb*NPTS + gl)*64;
    }
    // ---- layer 1 ----
    f32x4 acc[4];
    #pragma unroll
    for (int tc=0;tc<4;tc++) acc[tc]=zero4();
    #pragma unroll
    for (int kc=0;kc<2;kc++){
      f16x8 Bf = *(const f16x8*)(fr + kc*32 + q*8);
      #pragma unroll
      for (int tc=0;tc<4;tc++){
        f16x8 Af = *(const f16x8*)&Wf1[((tc*2+kc)*64+lane)*4];
        acc[tc] = MFMA16(Af,Bf,acc[tc]);
      }
    }
    {  // xyz chunk
      f16x8 Bf = *(const f16x8*)&Xs[colbase + 32 + q*4];
      #pragma unroll
      for (int tc=0;tc<4;tc++){
        f16x8 Af = zero8h();
        if (q==0){
          const int row = tc*16+n;
          Af[0]=(_Float16)W0raw[row*67+0];
          Af[1]=(_Float16)W0raw[row*67+1];
          Af[2]=(_Float16)W0raw[row*67+2];
        }
        acc[tc] = MFMA16(Af,Bf,acc[tc]);
      }
    }

    if constexpr (STAGE==0){
      #pragma unroll
      for (int tc=0;tc<4;tc++){
        #pragma unroll
        for (int r=0;r<4;r++){
          float s1=acc[tc][r], s2=__fmul_rn(s1,s1);
          #pragma unroll
          for (int off=1;off<16;off<<=1){ s1+=__shfl_xor(s1,off); s2+=__shfl_xor(s2,off); }
          if (n==0){ const int c=tc*16+q*4+r;
            atomicAdd(&bins[c], s1); atomicAdd(&bins[TCO+c], s2); }
        }
      }
    } else {
      #pragma unroll
      for (int tc=0;tc<4;tc++){
        const f32x4 sc4 = *(const f32x4*)&aff[tc*16+q*4];
        const f32x4 sh4 = *(const f32x4*)&aff[128+tc*16+q*4];
        Xs[colbase + tc*8+q*2]   = packh(fmaxf(fmaf(acc[tc][0],sc4[0],sh4[0]),0.f),
                                         fmaxf(fmaf(acc[tc][1],sc4[1],sh4[1]),0.f));
        Xs[colbase + tc*8+q*2+1] = packh(fmaxf(fmaf(acc[tc][2],sc4[2],sh4[2]),0.f),
                                         fmaxf(fmaf(acc[tc][3],sc4[3],sh4[3]),0.f));
      }
      // ---- layer 2 ----
      f32x4 acc2[4];
      #pragma unroll
      for (int tc=0;tc<4;tc++) acc2[tc]=zero4();
      #pragma unroll
      for (int kc=0;kc<2;kc++){
        f16x8 Bf = *(const f16x8*)&Xs[colbase + kc*16 + q*4];
        #pragma unroll
        for (int tc=0;tc<4;tc++){
          f16x8 Af = *(const f16x8*)&Wf2[((tc*2+kc)*64+lane)*4];
          acc2[tc] = MFMA16(Af,Bf,acc2[tc]);
        }
      }
      if constexpr (STAGE==1){
        #pragma unroll
        for (int tc=0;tc<4;tc++){
          #pragma unroll
          for (int r=0;r<4;r++){
            float s1=acc2[tc][r], s2=__fmul_rn(s1,s1);
            #pragma unroll
            for (int off=1;off<16;off<<=1){ s1+=__shfl_xor(s1,off); s2+=__shfl_xor(s2,off); }
            if (n==0){ const int c=tc*16+q*4+r;
              atomicAdd(&bins[c], s1); atomicAdd(&bins[TCO+c], s2); }
          }
        }
      } else {
        #pragma unroll
        for (int tc=0;tc<4;tc++){
          const f32x4 sc4 = *(const f32x4*)&aff[256+tc*16+q*4];
          const f32x4 sh4 = *(const f32x4*)&aff[256+128+tc*16+q*4];
          Xs[colbase + tc*8+q*2]   = packh(fmaxf(fmaf(acc2[tc][0],sc4[0],sh4[0]),0.f),
                                           fmaxf(fmaf(acc2[tc][1],sc4[1],sh4[1]),0.f));
          Xs[colbase + tc*8+q*2+1] = packh(fmaxf(fmaf(acc2[tc][2],sc4[2],sh4[2]),0.f),
                                           fmaxf(fmaf(acc2[tc][3],sc4[3],sh4[3]),0.f));
        }
        // ---- layer 3 ----
        f32x4 acc3[8];
        #pragma unroll
        for (int tc=0;tc<8;tc++) acc3[tc]=zero4();
        #pragma unroll
        for (int kc=0;kc<2;kc++){
          f16x8 Bf = *(const f16x8*)&Xs[colbase + kc*16 + q*4];
          #pragma unroll
          for (int tc=0;tc<8;tc++){
            f16x8 Af = *(const f16x8*)&Wf3[((tc*2+kc)*64+lane)*4];
            acc3[tc] = MFMA16(Af,Bf,acc3[tc]);
          }
        }
        u32* mmb = &mm[(ch&1)*512];
        #pragma unroll
        for (int tc=0;tc<8;tc++){
          #pragma unroll
          for (int r=0;r<4;r++){
            float y=acc3[tc][r];
            float s1=y, s2=__fmul_rn(y,y);
            u32 pm = packh(y, -y);
            #pragma unroll
            for (int off=1;off<16;off<<=1){
              s1+=__shfl_xor(s1,off); s2+=__shfl_xor(s2,off);
              u32 o = (u32)__shfl_xor((int)pm,off);
              pm = asU32(__builtin_elementwise_max(asH2(pm), asH2(o)));
            }
            if (n==0){ const int c=tc*16+q*4+r;
              atomicAdd(&bins[c], s1); atomicAdd(&bins[128+c], s2);
              mmb[w*128+c]=pm; }
          }
        }
        __syncthreads();
        {
          const int c = t&127, gg = t>>7;
          u32 a = mmb[(2*gg)*128+c], b2 = mmb[(2*gg+1)*128+c];
          h2v hm = __builtin_elementwise_max(asH2(a), asH2(b2));
          const int s0 = inner*8 + ch*2 + gg;
          outMM[((size_t)bb*128+c)*NS + s0] = packh((float)hm[0], -(float)hm[1]);
        }
      }
    }
  }

  __syncthreads();
  if (t < TCO){
    atomicAdd(&stats[STAGE*256 + 2*t],   bins[t]);
    atomicAdd(&stats[STAGE*256 + 2*t+1], bins[TCO+t]);
  }
}

// -------------------------------------------------------------- apply ----
// layer2 affine computed inline from stats seg 2 (identical op order as the
// old finalize_kernel).
__global__ __launch_bounds__(256) void apply_kernel(const float* __restrict__ stats,
    const float* __restrict__ g2, const float* __restrict__ b2,
    float* __restrict__ outF)
{
  __shared__ float a2[256];
  const int t = threadIdx.x;
  if (t < 128){
    const float mean = stats[512+2*t] * (1.f/524288.f);
    const float var  = fmaxf(stats[512+2*t+1] * (1.f/524288.f) - mean*mean, 0.f);
    const float rstd = 1.f / sqrtf(var + 1e-5f);
    const float s = rstd * g2[t];
    a2[t] = s; a2[128+t] = b2[t] - mean*s;
  }
  __syncthreads();
  const int i = blockIdx.x*256 + t;
  const int c = (i >> 10) & 127;
  u32 v = ((const u32*)outF)[i];
  h2v h = asH2(v);
  float sc = a2[c], sh = a2[128+c];
  float cand = (sc > 0.f) ? (float)h[0] : (float)h[1];
  outF[i] = fmaxf(fmaf(cand, sc, sh), 0.f);
}

// ------------------------------------------------------------- launch ----
extern "C" void kernel_launch(void* const* d_in, const int* in_sizes, int n_in,
                              void* d_out, int out_size, void* d_ws, size_t ws_size,
                              hipStream_t stream)
{
  (void)in_sizes; (void)n_in; (void)out_size; (void)ws_size;
  const float* xyz  = (const float*)d_in[0];
  const float* feat = (const float*)d_in[1];
  const float* W0 = (const float*)d_in[2];
  const float* g0 = (const float*)d_in[3];
  const float* b0 = (const float*)d_in[4];
  const float* W1 = (const float*)d_in[5];
  const float* g1 = (const float*)d_in[6];
  const float* b1 = (const float*)d_in[7];
  const float* W2 = (const float*)d_in[8];
  const float* g2 = (const float*)d_in[9];
  const float* b2 = (const float*)d_in[10];

  char* ws = (char*)d_ws;                       // 17,864,704 B (proven R14)
  u16*   fT     = (u16*)  (ws + 0);             // 16,777,216 B
  u16*   gidx   = (u16*)  (ws + 16777216);      //  1,048,576 B
  u32*   Wf1    = (u32*)  (ws + 17825792);      //      8192 B
  u32*   Wf2    = (u32*)  (ws + 17833984);      //      8192 B
  u32*   Wf3    = (u32*)  (ws + 17842176);      //     16384 B
  float* stats  = (float*)(ws + 17858560);      //      3072 B

  float* out_xyz  = (float*)d_out;                         // (16,3,1024) f32
  float* out_feat = (float*)d_out + (size_t)NB*3*NS;       // (16,128,1024) f32

  prep_kernel<<<1,256,0,stream>>>(W0,W1,W2,Wf1,Wf2,Wf3,stats);
  transpose_kernel<<<2048,256,0,stream>>>(feat, (u32*)fT);
  fps_kernel<<<NB,1024,0,stream>>>(xyz, out_xyz);
  ballq_kernel<<<NB*NS/4,256,0,stream>>>(xyz, out_xyz, gidx);

  mlp_pass<0><<<NSAMP/256,256,0,stream>>>(xyz,feat,out_xyz,gidx,fT,Wf1,Wf2,Wf3,W0,
                                          g0,b0,g0,b0, stats,(u32*)out_feat);
  mlp_pass<1><<<NSAMP/256,256,0,stream>>>(xyz,feat,out_xyz,gidx,fT,Wf1,Wf2,Wf3,W0,
                                          g0,b0,g0,b0, stats,(u32*)out_feat);
  mlp_pass<2><<<NSAMP/256,256,0,stream>>>(xyz,feat,out_xyz,gidx,fT,Wf1,Wf2,Wf3,W0,
                                          g0,b0,g1,b1, stats,(u32*)out_feat);
  apply_kernel<<<(NB*128*NS)/256,256,0,stream>>>(stats, g2, b2, out_feat);
}

// Round 14
// 1432.901 us; speedup vs baseline: 1.1899x; 1.0977x over previous
//
#include <hip/hip_runtime.h>

// PointNetSAModule on MI355X (gfx950).
// B=16, N=8192, CIN=64, S=1024, K=32, radius=0.2, MLP 67->64->64->128, eps=1e-5.
// Inputs/outputs float32. ws >= 17.9 MB proven (R14).
//
// R22 (MEASURED WIN: 1572.9us, fps 902.8us, conflicts 62K) -> R23:
//  * mlp_pass 16-lane reductions converted from __shfl_xor (ds_bpermute,
//    LDS pipe; STAGE2 = 1536 bpermute/thread) to DPP row ops (VALU pipe),
//    using the same 4-level mirror recipe already proven in fps
//    (xor1, xor2, row_half_mirror, row_mirror). Removes ~12.6M wave-level
//    LDS-pipe ops from pass<2> (+ ~1/3 in passes 0/1), decongesting the
//    pipe shared with Xs tile traffic and bins atomics.
//    Sum reassociation differs at levels 3-4 by ~ulps — far below the f16
//    quantization floor (absmax 0.03125); stats accumulation is already
//    order-nondeterministic via atomics. fps/ballq/prep/transpose untouched.

typedef unsigned short u16;
typedef unsigned int   u32;
typedef unsigned long long u64;

#define NB    16
#define NPTS  8192
#define CINF  64
#define NS    1024
#define KK    32
#define NSAMP (NB*NS*KK)   // 524288

typedef _Float16 h2v   __attribute__((ext_vector_type(2)));
typedef _Float16 f16x8 __attribute__((ext_vector_type(8)));
typedef float    f32x4 __attribute__((ext_vector_type(4)));
typedef float    f32x2 __attribute__((ext_vector_type(2)));

static __device__ __forceinline__ h2v asH2(u32 x){ union{u32 u; h2v h;} v; v.u=x; return v.h; }
static __device__ __forceinline__ u32 asU32(h2v h){ union{u32 u; h2v h;} v; v.h=h; return v.u; }
static __device__ __forceinline__ u32 packh(float lo, float hi){
  union{ _Float16 h[2]; u32 u; } v;
  v.h[0]=(_Float16)lo; v.h[1]=(_Float16)hi; return v.u;
}
static __device__ __forceinline__ u16 f16b(float z){
  union{ _Float16 h; u16 s; } v; v.h=(_Float16)z; return v.s;
}
static __device__ __forceinline__ f32x4 zero4(){ f32x4 z; z[0]=0.f;z[1]=0.f;z[2]=0.f;z[3]=0.f; return z; }
static __device__ __forceinline__ f16x8 zero8h(){
  f16x8 z;
  #pragma unroll
  for (int i=0;i<8;i++) z[i]=(_Float16)0.f;
  return z;
}

// exact-order d^2, matching numpy f32: (dx*dx + dy*dy) + dz*dz, no FMA contraction
static __device__ __forceinline__ float d2_exact(float ax,float ay,float az,float bx,float by,float bz){
  float dx=__fsub_rn(ax,bx), dy=__fsub_rn(ay,by), dz=__fsub_rn(az,bz);
  return __fadd_rn(__fadd_rn(__fmul_rn(dx,dx),__fmul_rn(dy,dy)),__fmul_rn(dz,dz));
}

// DPP helpers (VALU pipe)
template<int CTRL, int RMASK>
static __device__ __forceinline__ float dppfmax1(float v){
  int o = __builtin_amdgcn_update_dpp(__float_as_int(v), __float_as_int(v),
                                      CTRL, RMASK, 0xf, false);
  return fmaxf(v, __int_as_float(o));
}
template<int CTRL, int RMASK>
static __device__ __forceinline__ float dppfmin1(float v){
  int o = __builtin_amdgcn_update_dpp(__float_as_int(v), __float_as_int(v),
                                      CTRL, RMASK, 0xf, false);
  return fminf(v, __int_as_float(o));
}
template<int CTRL, int RMASK>
static __device__ __forceinline__ u32 dppumax1(u32 v){
  u32 o = (u32)__builtin_amdgcn_update_dpp((int)v, (int)v, CTRL, RMASK, 0xf, false);
  return v > o ? v : o;
}
template<int CTRL>
static __device__ __forceinline__ float dppfadd1(float v){
  int o = __builtin_amdgcn_update_dpp(__float_as_int(v), __float_as_int(v),
                                      CTRL, 0xf, 0xf, false);
  return v + __int_as_float(o);
}
template<int CTRL>
static __device__ __forceinline__ u32 dpph2max1(u32 v){
  u32 o = (u32)__builtin_amdgcn_update_dpp((int)v, (int)v, CTRL, 0xf, 0xf, false);
  return asU32(__builtin_elementwise_max(asH2(v), asH2(o)));
}
#define RED6MAX(v) { v=dppfmax1<0xB1,0xf>(v); v=dppfmax1<0x4E,0xf>(v); v=dppfmax1<0x141,0xf>(v); \
                     v=dppfmax1<0x140,0xf>(v); v=dppfmax1<0x142,0xa>(v); v=dppfmax1<0x143,0xc>(v); }
#define RED6MIN(v) { v=dppfmin1<0xB1,0xf>(v); v=dppfmin1<0x4E,0xf>(v); v=dppfmin1<0x141,0xf>(v); \
                     v=dppfmin1<0x140,0xf>(v); v=dppfmin1<0x142,0xa>(v); v=dppfmin1<0x143,0xc>(v); }
#define RED6UMAX(v) { v=dppumax1<0xB1,0xf>(v); v=dppumax1<0x4E,0xf>(v); v=dppumax1<0x141,0xf>(v); \
                      v=dppumax1<0x140,0xf>(v); v=dppumax1<0x142,0xa>(v); v=dppumax1<0x143,0xc>(v); }
// 4-level (within-row-of-16) full reduce: every lane of each 16-lane row
// ends holding the row result.
#define RED4MAXROW(v) { v=dppfmax1<0xB1,0xf>(v); v=dppfmax1<0x4E,0xf>(v); \
                        v=dppfmax1<0x141,0xf>(v); v=dppfmax1<0x140,0xf>(v); }
#define RED4UMAXROW(v) { v=dppumax1<0xB1,0xf>(v); v=dppumax1<0x4E,0xf>(v); \
                         v=dppumax1<0x141,0xf>(v); v=dppumax1<0x140,0xf>(v); }
#define RED4SUMROW(v)  { v=dppfadd1<0xB1>(v); v=dppfadd1<0x4E>(v); \
                         v=dppfadd1<0x141>(v); v=dppfadd1<0x140>(v); }
#define RED4H2MAXROW(v){ v=dpph2max1<0xB1>(v); v=dpph2max1<0x4E>(v); \
                         v=dpph2max1<0x141>(v); v=dpph2max1<0x140>(v); }

// ---------------------------------------------------------------- prep ----
__global__ void prep_kernel(const float* __restrict__ W0, const float* __restrict__ W1,
                            const float* __restrict__ W2,
                            u32* __restrict__ Wf1, u32* __restrict__ Wf2, u32* __restrict__ Wf3,
                            float* __restrict__ stats)
{
  const int t = threadIdx.x;
  for (int i=t;i<768;i+=256) stats[i]=0.f;
  for (int i=t;i<2048;i+=256){           // L1: 4 tiles x 2 chunks (feat cols only)
    int d=i&3, lane=(i>>2)&63, kc=(i>>8)&1, tc=i>>9;
    int row=tc*16+(lane&15), k0=kc*32+(lane>>4)*8+2*d;
    Wf1[i]=packh(W0[row*67+3+k0], W0[row*67+4+k0]);
  }
  for (int i=t;i<2048;i+=256){           // L2
    int d=i&3, lane=(i>>2)&63, kc=(i>>8)&1, tc=i>>9;
    int row=tc*16+(lane&15), k0=kc*32+(lane>>4)*8+2*d;
    Wf2[i]=packh(W1[row*64+k0], W1[row*64+k0+1]);
  }
  for (int i=t;i<4096;i+=256){           // L3
    int d=i&3, lane=(i>>2)&63, kc=(i>>8)&1, tc=i>>9;
    int row=tc*16+(lane&15), k0=kc*32+(lane>>4)*8+2*d;
    Wf3[i]=packh(W2[row*64+k0], W2[row*64+k0+1]);
  }
}

// ----------------------------------------------------- feat transpose ----
__global__ __launch_bounds__(256) void transpose_kernel(const float* __restrict__ feat,
                                                        u32* __restrict__ fT32)
{
  __shared__ u16 tile[64][65];
  const int b  = blockIdx.x >> 7;
  const int n0 = (blockIdx.x & 127) << 6;
  const int t = threadIdx.x;
  const int ln = t & 63, lc = t >> 6;
  #pragma unroll
  for (int cc=0; cc<64; cc+=4){
    const int c = cc + lc;
    tile[c][ln] = f16b(feat[((size_t)b*64 + c)*NPTS + n0 + ln]);
  }
  __syncthreads();
  #pragma unroll
  for (int i=0;i<8;i++){
    const int idx = t*8 + i;
    const int row = idx >> 5, dw = idx & 31;
    u32 pair = (u32)tile[2*dw][row] | ((u32)tile[2*dw+1][row] << 16);
    fT32[((size_t)b*NPTS + n0 + row)*32 + dw] = pair;
  }
}

// ----------------------------------------------------------------- FPS ----
// one block per batch; 1024 threads. Morton sort -> wave-compact regions,
// wave bbox prune (no-op skip). Update path entirely in registers; tail is
// value-then-match DPP over 16 wave records + one uniform broadcast LDS
// read of the winner's coords from sc[]. NO global ops inside the step loop:
// thread t captures the step-t center in registers; coalesced epilogue store.
__global__ __launch_bounds__(1024,1) void fps_kernel(const float* __restrict__ xyz,
    float* __restrict__ out_xyz)
{
  __shared__ float sc[1024*28];            // sorted coords: 8/thread x8|y8|z8|pad4
  __shared__ u16  sidx[NPTS];              // sorted slot -> orig idx
  __shared__ u32  hcnt[64], hoff[64];
  __shared__ u32  s_kv[2][16], s_ki[2][16];
  const int b = blockIdx.x, t = threadIdx.x;
  const float* xb = xyz + (size_t)b*3*NPTS;
  if (t<64) hcnt[t]=0;
  __syncthreads();
  // ---- pass 1: load (coalesced), Morton cell, histogram ----
  float lx[8], ly[8], lz[8]; int lcell[8];
  #pragma unroll
  for (int i=0;i<8;i++){
    const int idx = t + 1024*i;
    float x=xb[idx], y=xb[NPTS+idx], z=xb[2*NPTS+idx];
    lx[i]=x; ly[i]=y; lz[i]=z;
    int ix=(int)(x*4.f); ix = ix<0?0:(ix>3?3:ix);
    int iy=(int)(y*4.f); iy = iy<0?0:(iy>3?3:iy);
    int iz=(int)(z*4.f); iz = iz<0?0:(iz>3?3:iz);
    int m = (ix&1)|((iy&1)<<1)|((iz&1)<<2)|((ix&2)<<2)|((iy&2)<<3)|((iz&2)<<4);
    lcell[i]=m;
    atomicAdd(&hcnt[m],1u);
  }
  __syncthreads();
  if (t==0){ u32 s=0; for (int c=0;c<64;c++){ hoff[c]=s; s+=hcnt[c]; } }
  __syncthreads();
  // ---- scatter into sorted LDS layout ----
  #pragma unroll
  for (int i=0;i<8;i++){
    u32 pos = atomicAdd(&hoff[lcell[i]],1u);
    const int rb=(int)(pos>>3)*28+(int)(pos&7);
    sc[rb]=lx[i]; sc[rb+8]=ly[i]; sc[rb+16]=lz[i];
    sidx[pos]=(u16)(t+1024*i);
  }
  __syncthreads();
  // ---- pull this thread's 8 sorted points into registers; sc[] remains
  //      valid for the tail's winner-coord broadcast read ----
  const int tb = t*28;
  const f32x4 X0=*(const f32x4*)&sc[tb],   X1=*(const f32x4*)&sc[tb+4];
  const f32x4 Y0=*(const f32x4*)&sc[tb+8], Y1=*(const f32x4*)&sc[tb+12];
  const f32x4 Z0=*(const f32x4*)&sc[tb+16],Z1=*(const f32x4*)&sc[tb+20];
  // ---- wave bbox ----
  float mnx,mxx,mny,mxy,mnz,mxz;
  {
    mnx=mxx=X0[0]; mny=mxy=Y0[0]; mnz=mxz=Z0[0];
    #pragma unroll
    for (int i=0;i<4;i++){
      mnx=fminf(mnx,fminf(X0[i],X1[i])); mxx=fmaxf(mxx,fmaxf(X0[i],X1[i]));
      mny=fminf(mny,fminf(Y0[i],Y1[i])); mxy=fmaxf(mxy,fmaxf(Y0[i],Y1[i]));
      mnz=fminf(mnz,fminf(Z0[i],Z1[i])); mxz=fmaxf(mxz,fmaxf(Z0[i],Z1[i]));
    }
  }
  RED6MIN(mnx) RED6MIN(mny) RED6MIN(mnz)
  RED6MAX(mxx) RED6MAX(mxy) RED6MAX(mxz)
  const float bx0=__int_as_float(__builtin_amdgcn_readlane(__float_as_int(mnx),63));
  const float bx1=__int_as_float(__builtin_amdgcn_readlane(__float_as_int(mxx),63));
  const float by0=__int_as_float(__builtin_amdgcn_readlane(__float_as_int(mny),63));
  const float by1=__int_as_float(__builtin_amdgcn_readlane(__float_as_int(mxy),63));
  const float bz0=__int_as_float(__builtin_amdgcn_readlane(__float_as_int(mnz),63));
  const float bz1=__int_as_float(__builtin_amdgcn_readlane(__float_as_int(mxz),63));
  // hoisted: key constants (8192-orig)<<13 | slot  (>= 1<<13 > 0 always)
  u32 kb[8];
  {
    uint4 sp = *(const uint4*)&sidx[8*t];
    const u32 o0=sp.x&0xffffu, o1=sp.x>>16, o2=sp.y&0xffffu, o3=sp.y>>16;
    const u32 o4=sp.z&0xffffu, o5=sp.z>>16, o6=sp.w&0xffffu, o7=sp.w>>16;
    kb[0]=((8192u-o0)<<13)|(u32)(8*t+0); kb[1]=((8192u-o1)<<13)|(u32)(8*t+1);
    kb[2]=((8192u-o2)<<13)|(u32)(8*t+2); kb[3]=((8192u-o3)<<13)|(u32)(8*t+3);
    kb[4]=((8192u-o4)<<13)|(u32)(8*t+4); kb[5]=((8192u-o5)<<13)|(u32)(8*t+5);
    kb[6]=((8192u-o6)<<13)|(u32)(8*t+6); kb[7]=((8192u-o7)<<13)|(u32)(8*t+7);
  }

  f32x2 d[4];
  #pragma unroll
  for (int i=0;i<4;i++){ d[i][0]=__builtin_inff(); d[i][1]=__builtin_inff(); }
  u32 cached_kv = 0x7f800000u;           // +inf -> first step always updates
  u32 cached_ki = 0;

  float cx = xb[0], cy = xb[NPTS], cz = xb[2*NPTS];   // initial center = point 0
  float rx = 0.f, ry = 0.f, rz = 0.f;    // per-thread captured center (step == t)
  const int lane = t & 63, wv = t >> 6, l16 = lane & 15;
  for (int step=0; step<NS; step++){
    if (step == t){ rx = cx; ry = cy; rz = cz; }   // register capture, no vmem
    if (step==NS-1) break;
    // ---- wave-uniform prune test ----
    const float cval = __uint_as_float(cached_kv);
    float dxm = fmaxf(fmaxf(bx0-cx, cx-bx1), 0.f);
    float dym = fmaxf(fmaxf(by0-cy, cy-by1), 0.f);
    float dzm = fmaxf(fmaxf(bz0-cz, cz-bz1), 0.f);
    float lbs = ((dxm*dxm + dym*dym) + dzm*dzm) * 0.999f;   // conservative
    if (!(lbs > cval)){
      // ---- full update of this wave's 512 points (registers only) ----
      {
        #pragma clang fp contract(off)     // IEEE separate mul/add (numpy order)
        f32x2 cpx; cpx[0]=cx; cpx[1]=cx;
        f32x2 cpy; cpy[0]=cy; cpy[1]=cy;
        f32x2 cpz; cpz[0]=cz; cpz[1]=cz;
#define UPDP(pi, PX, PY, PZ) { \
        f32x2 dx = (PX) - cpx, dy = (PY) - cpy, dz = (PZ) - cpz; \
        f32x2 t1 = dx*dx; f32x2 t2 = dy*dy; f32x2 t3 = t1 + t2; \
        f32x2 t4 = dz*dz; f32x2 dd = t3 + t4; \
        d[pi] = __builtin_elementwise_min(dd, d[pi]); }
        UPDP(0, X0.lo, Y0.lo, Z0.lo)
        UPDP(1, X0.hi, Y0.hi, Z0.hi)
        UPDP(2, X1.lo, Y1.lo, Z1.lo)
        UPDP(3, X1.hi, Y1.hi, Z1.hi)
#undef UPDP
      }
      // value-only wave max
      f32x2 m0 = __builtin_elementwise_max(d[0], d[1]);
      f32x2 m1 = __builtin_elementwise_max(d[2], d[3]);
      f32x2 m2 = __builtin_elementwise_max(m0, m1);
      float bv = fmaxf(m2[0], m2[1]);
      RED6MAX(bv)                          // lane 63 valid
      const float wmax = __int_as_float(__builtin_amdgcn_readlane(__float_as_int(bv), 63));
      // matched-key recovery: parallel cndmask + umax tree (depth ~5)
      const u32 c0 = (d[0][0]==wmax)?kb[0]:0u;
      const u32 c1 = (d[0][1]==wmax)?kb[1]:0u;
      const u32 c2 = (d[1][0]==wmax)?kb[2]:0u;
      const u32 c3 = (d[1][1]==wmax)?kb[3]:0u;
      const u32 c4 = (d[2][0]==wmax)?kb[4]:0u;
      const u32 c5 = (d[2][1]==wmax)?kb[5]:0u;
      const u32 c6 = (d[3][0]==wmax)?kb[6]:0u;
      const u32 c7 = (d[3][1]==wmax)?kb[7]:0u;
      const u32 m01 = c0>c1?c0:c1, m23 = c2>c3?c2:c3;
      const u32 m45 = c4>c5?c4:c5, m67 = c6>c7?c6:c7;
      const u32 m03 = m01>m23?m01:m23, m47 = m45>m67?m45:m67;
      u32 ki = m03>m47?m03:m47;
      RED6UMAX(ki)                         // lane 63: max key = smallest orig
      cached_kv = __float_as_uint(wmax);
      cached_ki = (u32)__builtin_amdgcn_readlane((int)ki, 63);   // wave-uniform
    }
    const int p = step&1;                  // single barrier per step
    if (lane==0){ s_kv[p][wv]=cached_kv; s_ki[p][wv]=cached_ki; }
    __syncthreads();
    // ---- cross-wave: value-then-match within each 16-lane row ----
    const u32 kv2 = s_kv[p][l16], ki2 = s_ki[p][l16];
    const float kvf = __uint_as_float(kv2);
    float kvr = kvf;
    RED4MAXROW(kvr)                        // all lanes: row (=block) max value
    u32 mki = (kvf == kvr) ? ki2 : 0u;
    RED4UMAXROW(mki)                       // all lanes: winning key
    const int wslot = (int)((u32)__builtin_amdgcn_readfirstlane((int)mki) & 8191u);
    const int wb2 = (wslot>>3)*28, wi = wslot&7;
    cx = sc[wb2+wi]; cy = sc[wb2+8+wi]; cz = sc[wb2+16+wi];
  }
  // ---- epilogue: coalesced center store (the loop's only global output) ----
  out_xyz[(size_t)(b*3+0)*NS + t] = rx;
  out_xyz[(size_t)(b*3+1)*NS + t] = ry;
  out_xyz[(size_t)(b*3+2)*NS + t] = rz;
}

// ---------------------------------------------------------- ball query ----
__global__ __launch_bounds__(256) void ballq_kernel(const float* __restrict__ xyz,
    const float* __restrict__ out_xyz, u16* __restrict__ gidx)
{
  const int gid = blockIdx.x*4 + (threadIdx.x>>6);
  const int lane = threadIdx.x & 63;
  const int b = gid >> 10, s = gid & (NS-1);
  const float* xb = xyz + (size_t)b*3*NPTS;
  const float cx = out_xyz[(size_t)(b*3+0)*NS+s];
  const float cy = out_xyz[(size_t)(b*3+1)*NS+s];
  const float cz = out_xyz[(size_t)(b*3+2)*NS+s];
  u16* out = gidx + (size_t)gid*KK;
  int cnt=0, first=-1;
  for (int base=0; base<NPTS; base+=64){
    const int pidx = base + lane;
    float d2 = d2_exact(cx,cy,cz, xb[pidx], xb[NPTS+pidx], xb[2*NPTS+pidx]);
    bool within = d2 < 0.04f;
    unsigned long long m = __ballot(within);
    if (m){
      if (first<0) first = base + (__ffsll(m)-1);
      int pos = cnt + (int)__popcll(m & ((1ull<<lane)-1ull));
      if (within && pos<KK) out[pos]=(u16)pidx;
      cnt += (int)__popcll(m);
      if (cnt>=KK) break;
    }
  }
  if (first<0) first=0;
  for (int posi = cnt + lane; posi < KK; posi += 64) out[posi]=(u16)first;
}

// --------------------------------------------------------------- MLP -----
#define MFMA16(A,B,C) __builtin_amdgcn_mfma_f32_16x16x32_f16(A,B,C,0,0,0)

// STAGE 0: stats of layer1.  STAGE 1: layer1(affine0)+stats of layer2.
// STAGE 2: layer1+layer2(affine0/1)+layer3+stats+minmax panel.
// Affines are recomputed inline per block from stats (identical inputs and
// op order as the old finalize_kernel -> identical values in every block).
// R23: 16-lane reductions are DPP row ops (VALU pipe), not shfl (LDS pipe).
template<int STAGE>
__global__ __launch_bounds__(256,2) void mlp_pass(
    const float* __restrict__ xyz, const float* __restrict__ feat,
    const float* __restrict__ out_xyz, const u16* __restrict__ gidx,
    const u16* __restrict__ fT,
    const u32* __restrict__ Wf1, const u32* __restrict__ Wf2, const u32* __restrict__ Wf3,
    const float* __restrict__ W0raw,
    const float* __restrict__ gA, const float* __restrict__ bA,
    const float* __restrict__ gB, const float* __restrict__ bB,
    float* __restrict__ stats, u32* __restrict__ outMM)
{
  constexpr int TCO = (STAGE==2)?128:64;
  __shared__ alignas(16) u32 Xs[64*48];          // 12 KB
  __shared__ float bins[2*TCO];
  __shared__ u32 mm[(STAGE==2)? 2*4*128 : 4];    // double-buffered cross-wave panel
  __shared__ float aff[(STAGE>=1)? 448 : 4];     // inline affine (layout = old global)

  const int t = threadIdx.x;
  const int lane = t&63, w = t>>6, n = lane&15, q = lane>>4;
  const int j = t>>2, q4 = t&3;
  const int colbase = (w*16+n)*48;
  const int u_   = blockIdx.x;                   // XCD-affinity swizzle
  const int slot = u_ & 7, rr = u_ >> 3;
  const int bb   = slot*2 + (rr>>7);
  const int inner= rr & 127;
  if (t < 2*TCO) bins[t]=0.f;
  if constexpr (STAGE>=1){
    if (t < 64){                                 // layer0 affine from stats seg 0
      const float mean = stats[2*t] * (1.f/524288.f);
      const float var  = fmaxf(stats[2*t+1] * (1.f/524288.f) - mean*mean, 0.f);
      const float rstd = 1.f / sqrtf(var + 1e-5f);
      const float s0 = rstd * gA[t];
      aff[t] = s0; aff[128+t] = bA[t] - mean*s0;
    }
  }
  if constexpr (STAGE==2){
    if (t >= 64 && t < 128){                     // layer1 affine from stats seg 1
      const int c = t - 64;
      const float mean = stats[256+2*c] * (1.f/524288.f);
      const float var  = fmaxf(stats[256+2*c+1] * (1.f/524288.f) - mean*mean, 0.f);
      const float rstd = 1.f / sqrtf(var + 1e-5f);
      const float s1 = rstd * gB[c];
      aff[256+c] = s1; aff[384+c] = bB[c] - mean*s1;
    }
  }
  __syncthreads();

  #pragma unroll 1
  for (int ch=0; ch<4; ch++){
    const int ssb = (bb*128 + inner)*256 + ch*64;
    const int ss = ssb + j;
    const int s = (ss >> 5) & (NS-1);
    const int g = ((int)gidx[ss]) & (NPTS-1);
    {
      u32* Xrow = &Xs[j*48];
      if (q4==3){
        const float* xb = xyz + (size_t)bb*3*NPTS;
        float dx=__fsub_rn(xb[g],        out_xyz[(size_t)(bb*3+0)*NS+s]);
        float dy=__fsub_rn(xb[NPTS+g],   out_xyz[(size_t)(bb*3+1)*NS+s]);
        float dz=__fsub_rn(xb[2*NPTS+g], out_xyz[(size_t)(bb*3+2)*NS+s]);
        Xrow[32]=packh(dx,dy); Xrow[33]=packh(dz,0.f);
      }
      #pragma unroll
      for (int i=34+q4;i<48;i+=4) Xrow[i]=0;
    }
    const u16* fr;
    {
      const int gl = ((int)gidx[ssb + w*16 + n]) & (NPTS-1);
      fr = fT + ((size_t)bb*NPTS + gl)*64;
    }
    // ---- layer 1 ----
    f32x4 acc[4];
    #pragma unroll
    for (int tc=0;tc<4;tc++) acc[tc]=zero4();
    #pragma unroll
    for (int kc=0;kc<2;kc++){
      f16x8 Bf = *(const f16x8*)(fr + kc*32 + q*8);
      #pragma unroll
      for (int tc=0;tc<4;tc++){
        f16x8 Af = *(const f16x8*)&Wf1[((tc*2+kc)*64+lane)*4];
        acc[tc] = MFMA16(Af,Bf,acc[tc]);
      }
    }
    {  // xyz chunk
      f16x8 Bf = *(const f16x8*)&Xs[colbase + 32 + q*4];
      #pragma unroll
      for (int tc=0;tc<4;tc++){
        f16x8 Af = zero8h();
        if (q==0){
          const int row = tc*16+n;
          Af[0]=(_Float16)W0raw[row*67+0];
          Af[1]=(_Float16)W0raw[row*67+1];
          Af[2]=(_Float16)W0raw[row*67+2];
        }
        acc[tc] = MFMA16(Af,Bf,acc[tc]);
      }
    }

    if constexpr (STAGE==0){
      #pragma unroll
      for (int tc=0;tc<4;tc++){
        #pragma unroll
        for (int r=0;r<4;r++){
          float s1=acc[tc][r], s2=__fmul_rn(s1,s1);
          RED4SUMROW(s1) RED4SUMROW(s2)
          if (n==0){ const int c=tc*16+q*4+r;
            atomicAdd(&bins[c], s1); atomicAdd(&bins[TCO+c], s2); }
        }
      }
    } else {
      #pragma unroll
      for (int tc=0;tc<4;tc++){
        const f32x4 sc4 = *(const f32x4*)&aff[tc*16+q*4];
        const f32x4 sh4 = *(const f32x4*)&aff[128+tc*16+q*4];
        Xs[colbase + tc*8+q*2]   = packh(fmaxf(fmaf(acc[tc][0],sc4[0],sh4[0]),0.f),
                                         fmaxf(fmaf(acc[tc][1],sc4[1],sh4[1]),0.f));
        Xs[colbase + tc*8+q*2+1] = packh(fmaxf(fmaf(acc[tc][2],sc4[2],sh4[2]),0.f),
                                         fmaxf(fmaf(acc[tc][3],sc4[3],sh4[3]),0.f));
      }
      // ---- layer 2 ----
      f32x4 acc2[4];
      #pragma unroll
      for (int tc=0;tc<4;tc++) acc2[tc]=zero4();
      #pragma unroll
      for (int kc=0;kc<2;kc++){
        f16x8 Bf = *(const f16x8*)&Xs[colbase + kc*16 + q*4];
        #pragma unroll
        for (int tc=0;tc<4;tc++){
          f16x8 Af = *(const f16x8*)&Wf2[((tc*2+kc)*64+lane)*4];
          acc2[tc] = MFMA16(Af,Bf,acc2[tc]);
        }
      }
      if constexpr (STAGE==1){
        #pragma unroll
        for (int tc=0;tc<4;tc++){
          #pragma unroll
          for (int r=0;r<4;r++){
            float s1=acc2[tc][r], s2=__fmul_rn(s1,s1);
            RED4SUMROW(s1) RED4SUMROW(s2)
            if (n==0){ const int c=tc*16+q*4+r;
              atomicAdd(&bins[c], s1); atomicAdd(&bins[TCO+c], s2); }
          }
        }
      } else {
        #pragma unroll
        for (int tc=0;tc<4;tc++){
          const f32x4 sc4 = *(const f32x4*)&aff[256+tc*16+q*4];
          const f32x4 sh4 = *(const f32x4*)&aff[256+128+tc*16+q*4];
          Xs[colbase + tc*8+q*2]   = packh(fmaxf(fmaf(acc2[tc][0],sc4[0],sh4[0]),0.f),
                                           fmaxf(fmaf(acc2[tc][1],sc4[1],sh4[1]),0.f));
          Xs[colbase + tc*8+q*2+1] = packh(fmaxf(fmaf(acc2[tc][2],sc4[2],sh4[2]),0.f),
                                           fmaxf(fmaf(acc2[tc][3],sc4[3],sh4[3]),0.f));
        }
        // ---- layer 3 ----
        f32x4 acc3[8];
        #pragma unroll
        for (int tc=0;tc<8;tc++) acc3[tc]=zero4();
        #pragma unroll
        for (int kc=0;kc<2;kc++){
          f16x8 Bf = *(const f16x8*)&Xs[colbase + kc*16 + q*4];
          #pragma unroll
          for (int tc=0;tc<8;tc++){
            f16x8 Af = *(const f16x8*)&Wf3[((tc*2+kc)*64+lane)*4];
            acc3[tc] = MFMA16(Af,Bf,acc3[tc]);
          }
        }
        u32* mmb = &mm[(ch&1)*512];
        #pragma unroll
        for (int tc=0;tc<8;tc++){
          #pragma unroll
          for (int r=0;r<4;r++){
            float y=acc3[tc][r];
            float s1=y, s2=__fmul_rn(y,y);
            u32 pm = packh(y, -y);
            RED4SUMROW(s1) RED4SUMROW(s2) RED4H2MAXROW(pm)
            if (n==0){ const int c=tc*16+q*4+r;
              atomicAdd(&bins[c], s1); atomicAdd(&bins[128+c], s2);
              mmb[w*128+c]=pm; }
          }
        }
        __syncthreads();
        {
          const int c = t&127, gg = t>>7;
          u32 a = mmb[(2*gg)*128+c], b2 = mmb[(2*gg+1)*128+c];
          h2v hm = __builtin_elementwise_max(asH2(a), asH2(b2));
          const int s0 = inner*8 + ch*2 + gg;
          outMM[((size_t)bb*128+c)*NS + s0] = packh((float)hm[0], -(float)hm[1]);
        }
      }
    }
  }

  __syncthreads();
  if (t < TCO){
    atomicAdd(&stats[STAGE*256 + 2*t],   bins[t]);
    atomicAdd(&stats[STAGE*256 + 2*t+1], bins[TCO+t]);
  }
}

// -------------------------------------------------------------- apply ----
// layer2 affine computed inline from stats seg 2 (identical op order as the
// old finalize_kernel).
__global__ __launch_bounds__(256) void apply_kernel(const float* __restrict__ stats,
    const float* __restrict__ g2, const float* __restrict__ b2,
    float* __restrict__ outF)
{
  __shared__ float a2[256];
  const int t = threadIdx.x;
  if (t < 128){
    const float mean = stats[512+2*t] * (1.f/524288.f);
    const float var  = fmaxf(stats[512+2*t+1] * (1.f/524288.f) - mean*mean, 0.f);
    const float rstd = 1.f / sqrtf(var + 1e-5f);
    const float s = rstd * g2[t];
    a2[t] = s; a2[128+t] = b2[t] - mean*s;
  }
  __syncthreads();
  const int i = blockIdx.x*256 + t;
  const int c = (i >> 10) & 127;
  u32 v = ((const u32*)outF)[i];
  h2v h = asH2(v);
  float sc = a2[c], sh = a2[128+c];
  float cand = (sc > 0.f) ? (float)h[0] : (float)h[1];
  outF[i] = fmaxf(fmaf(cand, sc, sh), 0.f);
}

// ------------------------------------------------------------- launch ----
extern "C" void kernel_launch(void* const* d_in, const int* in_sizes, int n_in,
                              void* d_out, int out_size, void* d_ws, size_t ws_size,
                              hipStream_t stream)
{
  (void)in_sizes; (void)n_in; (void)out_size; (void)ws_size;
  const float* xyz  = (const float*)d_in[0];
  const float* feat = (const float*)d_in[1];
  const float* W0 = (const float*)d_in[2];
  const float* g0 = (const float*)d_in[3];
  const float* b0 = (const float*)d_in[4];
  const float* W1 = (const float*)d_in[5];
  const float* g1 = (const float*)d_in[6];
  const float* b1 = (const float*)d_in[7];
  const float* W2 = (const float*)d_in[8];
  const float* g2 = (const float*)d_in[9];
  const float* b2 = (const float*)d_in[10];

  char* ws = (char*)d_ws;                       // 17,864,704 B (proven R14)
  u16*   fT     = (u16*)  (ws + 0);             // 16,777,216 B
  u16*   gidx   = (u16*)  (ws + 16777216);      //  1,048,576 B
  u32*   Wf1    = (u32*)  (ws + 17825792);      //      8192 B
  u32*   Wf2    = (u32*)  (ws + 17833984);      //      8192 B
  u32*   Wf3    = (u32*)  (ws + 17842176);      //     16384 B
  float* stats  = (float*)(ws + 17858560);      //      3072 B

  float* out_xyz  = (float*)d_out;                         // (16,3,1024) f32
  float* out_feat = (float*)d_out + (size_t)NB*3*NS;       // (16,128,1024) f32

  prep_kernel<<<1,256,0,stream>>>(W0,W1,W2,Wf1,Wf2,Wf3,stats);
  transpose_kernel<<<2048,256,0,stream>>>(feat, (u32*)fT);
  fps_kernel<<<NB,1024,0,stream>>>(xyz, out_xyz);
  ballq_kernel<<<NB*NS/4,256,0,stream>>>(xyz, out_xyz, gidx);

  mlp_pass<0><<<NSAMP/256,256,0,stream>>>(xyz,feat,out_xyz,gidx,fT,Wf1,Wf2,Wf3,W0,
                                          g0,b0,g0,b0, stats,(u32*)out_feat);
  mlp_pass<1><<<NSAMP/256,256,0,stream>>>(xyz,feat,out_xyz,gidx,fT,Wf1,Wf2,Wf3,W0,
                                          g0,b0,g0,b0, stats,(u32*)out_feat);
  mlp_pass<2><<<NSAMP/256,256,0,stream>>>(xyz,feat,out_xyz,gidx,fT,Wf1,Wf2,Wf3,W0,
                                          g0,b0,g1,b1, stats,(u32*)out_feat);
  apply_kernel<<<(NB*128*NS)/256,256,0,stream>>>(stats, g2, b2, out_feat);
}